// Round 6
// baseline (384.266 us; speedup 1.0000x reference)
//
#include <hip/hip_runtime.h>

// ---------------------------------------------------------------------------
// SAM vision attention (B=1, H=W=64, C=768, 12 heads x hd=64). fp32 I/O.
// cvt -> QKV proj (128-tile) -> rel_h/rel_w -> flash attn (split-K) ->
//   combine -> out proj
// MFMA v_mfma_f32_16x16x32_bf16 layouts (guide-verified m89/m91):
//   A/B frag: [m|n = lane&15][k = (lane>>4)*8 + j]   (8 bf16 / lane, b128)
//   C/D     : col = lane&15, row = (lane>>4)*4 + reg (4 f32 / lane)
// R15 = R14 + attn2 split-4 (occupancy 3->4 blocks/CU).
// Post-mortem ledger:
//   R10 (78.5us): reg-staged K/V, srh LDS, 2 barriers/tile. Proven base.
//   R11 (90.9us): gl_lds dbuf single-barrier REGRESSED (m99/m100 repro).
//   R12 (90.3us): per-tile scalar rel_h globals stall barrier drains.
//   R13 (285us!): K/V in kf[8]/vf[8] regs -> 128+ VGPR demand vs 84 alloc ->
//                 scratch spill. Do VGPR arithmetic first.
//   R14 (75.8us): R10 staging + math (Q pre-scale, bias-in-C, bare exp2). ✓
//   R15: attn2 issue-busy 68%/stall 32% at 12 waves/CU (LDS-capped 3 blk/CU,
//        grid exactly 3/CU). Split-4: srh halves (2 ki-octs) -> LDS 38912 ->
//        4 blk/CU, grid 1536. exp2 is ~26% of attn2 (201M trans ops,
//        irreducible) -> gains must come from overlap, i.e. waves.
// Math (validated R11/R12/R14): Q pre-scaled by SC=0.125*log2e in qkv;
// relk osc=8 so rhb/rwb hold rel*log2e; attn2 inits QK accumulator to rh+rw
// (bias-in-C); softmax is a bare v_exp_f32.
// ---------------------------------------------------------------------------

typedef __attribute__((ext_vector_type(8))) short bf16x8;
typedef __attribute__((ext_vector_type(4))) float f32x4;
typedef __attribute__((ext_vector_type(4))) short s16x4;
typedef __attribute__((ext_vector_type(2))) unsigned int u32x2;
typedef __attribute__((ext_vector_type(4))) unsigned int u32x4;

__device__ __forceinline__ float b2f(unsigned short h) {
    union { unsigned int u; float f; } v; v.u = ((unsigned int)h) << 16; return v.f;
}
__device__ __forceinline__ unsigned short f2b(float f) {
    union { float f; unsigned int u; } v; v.f = f;
    unsigned int r = v.u + 0x7FFFu + ((v.u >> 16) & 1u);  // RNE
    return (unsigned short)(r >> 16);
}
__device__ __forceinline__ void gl_lds16(const void* g, void* l) {
    __builtin_amdgcn_global_load_lds(
        (const __attribute__((address_space(1))) void*)g,
        (__attribute__((address_space(3))) void*)l, 16, 0, 0);
}

// ---------------------------------------------------------------------------
// fp32 -> bf16 bulk convert into one contiguous region (quad-indexed).
// ---------------------------------------------------------------------------
__global__ __launch_bounds__(256) void cvt_bf16(
        const float* __restrict__ hs, const float* __restrict__ wq,
        const float* __restrict__ wk, const float* __restrict__ wv,
        const float* __restrict__ wo, const float* __restrict__ rph,
        const float* __restrict__ rpw, unsigned short* __restrict__ dst) {
    const int idx = blockIdx.x * 256 + threadIdx.x;
    if (idx >= 1380320) return;
    const float* src;
    int off;
    if      (idx < 786432)  { src = hs;  off = idx; }
    else if (idx < 933888)  { src = wq;  off = idx - 786432; }
    else if (idx < 1081344) { src = wk;  off = idx - 933888; }
    else if (idx < 1228800) { src = wv;  off = idx - 1081344; }
    else if (idx < 1376256) { src = wo;  off = idx - 1228800; }
    else if (idx < 1378288) { src = rph; off = idx - 1376256; }
    else                    { src = rpw; off = idx - 1378288; }
    const float4 v = ((const float4*)src)[off];
    s16x4 o;
    o[0] = (short)f2b(v.x); o[1] = (short)f2b(v.y);
    o[2] = (short)f2b(v.z); o[3] = (short)f2b(v.w);
    *(s16x4*)(dst + (size_t)idx * 4) = o;
}

// ---------------------------------------------------------------------------
// Fused QKV projection, 128x128 tile. z: 0->q (PRE-SCALED by 0.125*log2e),
// 1->k [n>>6][m][n&63]; 2->v^T token-PERMUTED, stored via LDS transpose.
// K-loop: double-buffered gl_lds, one barrier per step.
// ---------------------------------------------------------------------------
__launch_bounds__(256, 3)
__global__ void qkv128(const unsigned short* __restrict__ X,
                       const unsigned short* __restrict__ Wq,
                       const unsigned short* __restrict__ Wk,
                       const unsigned short* __restrict__ Wv,
                       const float* __restrict__ bq,
                       const float* __restrict__ bk,
                       const float* __restrict__ bv,
                       unsigned short* __restrict__ qb,
                       unsigned short* __restrict__ kb,
                       unsigned short* __restrict__ vtb) {
    __shared__ __align__(16) unsigned short sarena[16384];  // 2 x (A 4096 + B 4096)
    const int tid = threadIdx.x, lane = tid & 63, w = tid >> 6;
    const int r = lane & 15, quad = lane >> 4;
    const int nt = blockIdx.x, mt = blockIdx.y, z = blockIdx.z;
    const unsigned short* W  = (z == 0) ? Wq : (z == 1) ? Wk : Wv;
    const float*          Bv = (z == 0) ? bq : (z == 1) ? bk : bv;
    unsigned short*     outp = (z == 0) ? qb : (z == 1) ? kb : vtb;
    const float qsc = (z == 0) ? 0.18033688f : 1.0f;  // 0.125*log2(e)

    const int c0 = w * 64 + lane, c1 = c0 + 256;
    const unsigned short* xs0 = X + (mt * 128 + (c0 & 127)) * 768 + (c0 >> 7) * 8;
    const unsigned short* xs1 = X + (mt * 128 + (c1 & 127)) * 768 + (c1 >> 7) * 8;
    const unsigned short* ws0 = W + (nt * 128 + (c0 & 127)) * 768 + (c0 >> 7) * 8;
    const unsigned short* ws1 = W + (nt * 128 + (c1 & 127)) * 768 + (c1 >> 7) * 8;

    // prologue: stage kt=0 into buffer 0
    gl_lds16(xs0, &sarena[w * 512]);
    gl_lds16(xs1, &sarena[2048 + w * 512]);
    gl_lds16(ws0, &sarena[4096 + w * 512]);
    gl_lds16(ws1, &sarena[4096 + 2048 + w * 512]);
    __syncthreads();

    const int wr = (w & 1) * 64, wc = (w >> 1) * 64;
    f32x4 acc[4][4] = {};
    int cur = 0;
#pragma unroll 2
    for (int kt = 0; kt < 24; ++kt) {
        if (kt < 23) {              // issue next K-step into alt buffer
            const int nx = (cur ^ 1) * 8192;
            gl_lds16(xs0 + (kt + 1) * 32, &sarena[nx + w * 512]);
            gl_lds16(xs1 + (kt + 1) * 32, &sarena[nx + 2048 + w * 512]);
            gl_lds16(ws0 + (kt + 1) * 32, &sarena[nx + 4096 + w * 512]);
            gl_lds16(ws1 + (kt + 1) * 32, &sarena[nx + 4096 + 2048 + w * 512]);
        }
        const unsigned short* ab = &sarena[cur * 8192];
        const unsigned short* bb = ab + 4096;
        bf16x8 af[4], bfr[4];
#pragma unroll
        for (int i = 0; i < 4; ++i)
            af[i] = *(const bf16x8*)&ab[(quad * 128 + wr + i * 16 + r) * 8];
#pragma unroll
        for (int j = 0; j < 4; ++j)
            bfr[j] = *(const bf16x8*)&bb[(quad * 128 + wc + j * 16 + r) * 8];
#pragma unroll
        for (int i = 0; i < 4; ++i)
#pragma unroll
            for (int j = 0; j < 4; ++j)
                acc[i][j] = __builtin_amdgcn_mfma_f32_16x16x32_bf16(af[i], bfr[j], acc[i][j], 0, 0, 0);
        __syncthreads();            // drains vmcnt(0): next tile landed+visible
        cur ^= 1;
    }
    if (z < 2) {
#pragma unroll
        for (int j = 0; j < 4; ++j) {
            const int n = nt * 128 + wc + j * 16 + r;
            const float bias = Bv[n];
            const int nhi = n >> 6, nlo = n & 63;
#pragma unroll
            for (int i = 0; i < 4; ++i) {
#pragma unroll
                for (int reg = 0; reg < 4; ++reg) {
                    const int m = mt * 128 + wr + i * 16 + quad * 4 + reg;
                    outp[(nhi * 4096 + m) * 64 + nlo] = f2b((acc[i][j][reg] + bias) * qsc);
                }
            }
        }
    } else {
#pragma unroll
        for (int pass = 0; pass < 2; ++pass) {
            if ((w >> 1) == pass) {
#pragma unroll
                for (int j = 0; j < 4; ++j) {
                    const int n_l = j * 16 + r;
                    const float bias = Bv[nt * 128 + pass * 64 + n_l];
                    const int sw = (n_l & 7) << 4;
#pragma unroll
                    for (int reg = 0; reg < 4; ++reg) {
                        const int tokb = (wr + (quad * 4 + reg) * 4) ^ sw;
                        u32x2 d2;
                        d2.x = (unsigned int)f2b(acc[0][j][reg] + bias)
                             | ((unsigned int)f2b(acc[1][j][reg] + bias) << 16);
                        d2.y = (unsigned int)f2b(acc[2][j][reg] + bias)
                             | ((unsigned int)f2b(acc[3][j][reg] + bias) << 16);
                        *(u32x2*)&sarena[n_l * 128 + tokb] = d2;
                    }
                }
            }
            __syncthreads();
#pragma unroll
            for (int c = 0; c < 4; ++c) {
                const int u = c * 256 + tid;
                const int n_l = u >> 4, g = u & 15;
                const int phys = n_l * 128 + ((g * 8) ^ ((n_l & 7) << 4));
                bf16x8 val = *(const bf16x8*)&sarena[phys];
                *(bf16x8*)&outp[(size_t)(nt * 128 + pass * 64 + n_l) * 4096
                                + mt * 128 + g * 8] = val;
            }
            __syncthreads();
        }
    }
}

// ---------------------------------------------------------------------------
// Output projection, 128x128 tile, fp32 row-major out. Same dbuf K-loop.
// ---------------------------------------------------------------------------
__launch_bounds__(256, 3)
__global__ void out128(const unsigned short* __restrict__ X,
                       const unsigned short* __restrict__ W,
                       const float* __restrict__ Bv,
                       float* __restrict__ out) {
    __shared__ __align__(16) unsigned short sarena[16384];
    const int tid = threadIdx.x, lane = tid & 63, w = tid >> 6;
    const int r = lane & 15, quad = lane >> 4;
    const int nt = blockIdx.x, mt = blockIdx.y;

    const int c0 = w * 64 + lane, c1 = c0 + 256;
    const unsigned short* xs0 = X + (mt * 128 + (c0 & 127)) * 768 + (c0 >> 7) * 8;
    const unsigned short* xs1 = X + (mt * 128 + (c1 & 127)) * 768 + (c1 >> 7) * 8;
    const unsigned short* ws0 = W + (nt * 128 + (c0 & 127)) * 768 + (c0 >> 7) * 8;
    const unsigned short* ws1 = W + (nt * 128 + (c1 & 127)) * 768 + (c1 >> 7) * 8;

    gl_lds16(xs0, &sarena[w * 512]);
    gl_lds16(xs1, &sarena[2048 + w * 512]);
    gl_lds16(ws0, &sarena[4096 + w * 512]);
    gl_lds16(ws1, &sarena[4096 + 2048 + w * 512]);
    __syncthreads();

    const int wr = (w & 1) * 64, wc = (w >> 1) * 64;
    f32x4 acc[4][4] = {};
    int cur = 0;
#pragma unroll 2
    for (int kt = 0; kt < 24; ++kt) {
        if (kt < 23) {
            const int nx = (cur ^ 1) * 8192;
            gl_lds16(xs0 + (kt + 1) * 32, &sarena[nx + w * 512]);
            gl_lds16(xs1 + (kt + 1) * 32, &sarena[nx + 2048 + w * 512]);
            gl_lds16(ws0 + (kt + 1) * 32, &sarena[nx + 4096 + w * 512]);
            gl_lds16(ws1 + (kt + 1) * 32, &sarena[nx + 4096 + 2048 + w * 512]);
        }
        const unsigned short* ab = &sarena[cur * 8192];
        const unsigned short* bb = ab + 4096;
        bf16x8 af[4], bfr[4];
#pragma unroll
        for (int i = 0; i < 4; ++i)
            af[i] = *(const bf16x8*)&ab[(quad * 128 + wr + i * 16 + r) * 8];
#pragma unroll
        for (int j = 0; j < 4; ++j)
            bfr[j] = *(const bf16x8*)&bb[(quad * 128 + wc + j * 16 + r) * 8];
#pragma unroll
        for (int i = 0; i < 4; ++i)
#pragma unroll
            for (int j = 0; j < 4; ++j)
                acc[i][j] = __builtin_amdgcn_mfma_f32_16x16x32_bf16(af[i], bfr[j], acc[i][j], 0, 0, 0);
        __syncthreads();
        cur ^= 1;
    }
#pragma unroll
    for (int j = 0; j < 4; ++j) {
        const int n = nt * 128 + wc + j * 16 + r;
        const float bias = Bv[n];
#pragma unroll
        for (int i = 0; i < 4; ++i) {
#pragma unroll
            for (int reg = 0; reg < 4; ++reg) {
                const int m = mt * 128 + wr + i * 16 + quad * 4 + reg;
                out[m * 768 + n] = acc[i][j][reg] + bias;
            }
        }
    }
}

// ---------------------------------------------------------------------------
// rel_h / rel_w: per (head, a) 64x64x64 GEMM against gathered rel_pos rows.
// q is pre-scaled by SC=0.125*log2e, so osc=8 yields rel*log2e for BOTH modes.
// ---------------------------------------------------------------------------
__launch_bounds__(256, 4)
__global__ void relk(const unsigned short* __restrict__ qbuf,
                     const unsigned short* __restrict__ rph,
                     const unsigned short* __restrict__ rpw,
                     unsigned short* __restrict__ rh,
                     unsigned short* __restrict__ rw) {
    __shared__ __align__(16) unsigned short abuf[8 * 64 * 8];
    __shared__ __align__(16) unsigned short bbuf[8 * 64 * 8];
    const int tid = threadIdx.x;
    const int lane = tid & 63, w = tid >> 6;
    const int r = lane & 15, quad = lane >> 4;
    const int a = blockIdx.x, h = blockIdx.y, mode = blockIdx.z;
    const unsigned short* rp = mode ? rpw : rph;
    const float osc = 8.0f;  // log2e / SC

#pragma unroll
    for (int gg = 0; gg < 2; ++gg) {
        const int g = w * 2 + gg;
        const int arow = mode ? (h * 4096 + lane * 64 + a) : (h * 4096 + a * 64 + lane);
        gl_lds16(qbuf + arow * 64 + g * 8, &abuf[g * 512]);
        const int bidx = a - lane + 63;
        gl_lds16(rp + bidx * 64 + g * 8, &bbuf[g * 512]);
    }
    __syncthreads();

    f32x4 acc[4] = {};
#pragma unroll
    for (int s = 0; s < 2; ++s) {
        bf16x8 af = *(const bf16x8*)&abuf[((s * 4 + quad) * 64 + w * 16 + r) * 8];
#pragma unroll
        for (int j = 0; j < 4; ++j) {
            bf16x8 bfr = *(const bf16x8*)&bbuf[((s * 4 + quad) * 64 + j * 16 + r) * 8];
            acc[j] = __builtin_amdgcn_mfma_f32_16x16x32_bf16(af, bfr, acc[j], 0, 0, 0);
        }
    }
    unsigned short* out = mode ? rw : rh;
#pragma unroll
    for (int j = 0; j < 4; ++j) {
#pragma unroll
        for (int reg = 0; reg < 4; ++reg) {
            const int m = w * 16 + quad * 4 + reg, n = j * 16 + r;
            const int t = mode ? (h * 4096 + m * 64 + a) : (h * 4096 + a * 64 + m);
            out[t * 64 + n] = f2b(acc[j][reg] * osc);
        }
    }
}

// ---------------------------------------------------------------------------
// Flash attention, SPLIT-4: block = 128-query tile (2 qgroups of 16 / wave),
// split sp covers key tiles sp*16..sp*16+15 (ki = t for key-tile t).
// Fixed softmax ref (m=0). Per-tile structure (R14-proven):
//   issue global_load_dwordx4 (K,V tile t+1 -> 16 staging VGPRs)
//   rh2 <- srh LDS; acc init = rh2+rwL (bias-in-C)
//   -> QK MFMA -> bare v_exp_f32 + pack -> PV MFMA (+ ones-MFMA row-sum l)
//   barrier (vmcnt drain covers loads issued a phase ago)
//   ds_write K/V regs -> LDS ; barrier.
// LDS 38912 B -> 4 blocks/CU (16 waves) vs R14's 3 (12 waves).
// ---------------------------------------------------------------------------
__launch_bounds__(256, 4)
__global__ void attn2(const unsigned short* __restrict__ qbuf,
                      const unsigned short* __restrict__ kbuf,
                      const unsigned short* __restrict__ vtbuf,
                      const unsigned short* __restrict__ rhb,
                      const unsigned short* __restrict__ rwb,
                      float* __restrict__ po, float* __restrict__ lp) {
    __shared__ __align__(16) unsigned short skb[4096];   // K [d_oct][key][8]
    __shared__ __align__(16) unsigned short svb[4096];   // V^T [scol_oct][d][8]
    __shared__ __align__(16) unsigned short spb[9216];   // P x2 groups, stride 72
    __shared__ __align__(16) unsigned short srh[2048];   // rel_h*L2E, split's 2 octs
    const int tid = threadIdx.x;
    const int lane = tid & 63, w = tid >> 6;
    const int r = lane & 15, quad = lane >> 4;
    const int qt = blockIdx.x, h = blockIdx.y, sp = blockIdx.z;

    // srh: rel_h*log2e, this split's 2 ki-octs (ki = sp*16 .. sp*16+15)
    {
        const int ql = (w & 1) * 64 + lane;
        gl_lds16(rhb + (h * 4096 + qt * 128 + ql) * 64 + (sp * 2 + (w >> 1)) * 8,
                 &srh[w * 512]);
    }
    // per-thread K/V staging sources (16B per lane per oct; octs w*2, w*2+1)
    const unsigned short* ksrc = kbuf + (size_t)(h * 4096 + lane) * 64 + w * 16;
    const unsigned short* vsrc = vtbuf + (size_t)(h * 64 + lane) * 4096 + w * 16;
    u32x4 kp0, kp1, vp0, vp1;
    {
        const int t0 = sp * 16;
        kp0 = *(const u32x4*)(ksrc + (size_t)t0 * 4096);
        kp1 = *(const u32x4*)(ksrc + (size_t)t0 * 4096 + 8);
        vp0 = *(const u32x4*)(vsrc + t0 * 64);
        vp1 = *(const u32x4*)(vsrc + t0 * 64 + 8);
    }
    bf16x8 qf[2][2];
#pragma unroll
    for (int g = 0; g < 2; ++g) {
        const unsigned short* qrow =
            qbuf + (h * 4096 + qt * 128 + g * 64 + w * 16 + r) * 64;
        qf[g][0] = *(const bf16x8*)(qrow + quad * 8);
        qf[g][1] = *(const bf16x8*)(qrow + 32 + quad * 8);
    }
    float rwL[2][4][4];
#pragma unroll
    for (int g = 0; g < 2; ++g) {
        const unsigned short* rwrow = rwb + (h * 4096 + qt * 128 + g * 64) * 64;
#pragma unroll
        for (int reg = 0; reg < 4; ++reg) {
            const int ql = w * 16 + quad * 4 + reg;
#pragma unroll
            for (int j = 0; j < 4; ++j)
                rwL[g][j][reg] = b2f(rwrow[ql * 64 + j * 16 + r]);  // already *log2e
        }
    }
    bf16x8 onesf;
#pragma unroll
    for (int i = 0; i < 8; ++i) onesf[i] = (short)0x3F80;  // bf16 1.0

    f32x4 lacc[2] = {};
    f32x4 oacc[2][4] = {};
    __syncthreads();                 // srh staged + tile-0 loads complete
    *(u32x4*)&skb[(w * 128 + lane) * 8]      = kp0;
    *(u32x4*)&skb[(w * 128 + 64 + lane) * 8] = kp1;
    *(u32x4*)&svb[(w * 128 + lane) * 8]      = vp0;
    *(u32x4*)&svb[(w * 128 + 64 + lane) * 8] = vp1;
    __syncthreads();                 // tile-0 visible

    for (int tl = 0; tl < 16; ++tl) {
        const int t = sp * 16 + tl;
        if (tl < 15) {               // issue next-tile loads (awaited at barrier1)
            kp0 = *(const u32x4*)(ksrc + (size_t)(t + 1) * 4096);
            kp1 = *(const u32x4*)(ksrc + (size_t)(t + 1) * 4096 + 8);
            vp0 = *(const u32x4*)(vsrc + (t + 1) * 64);
            vp1 = *(const u32x4*)(vsrc + (t + 1) * 64 + 8);
        }
        // bias-in-C: acc starts at rh+rw (both already in log2 units)
        float rh2f[8];
#pragma unroll
        for (int i = 0; i < 8; ++i)
            rh2f[i] = b2f(srh[((tl >> 3) * 128 + (i >> 2) * 64 + w * 16
                               + quad * 4 + (i & 3)) * 8 + (t & 7)]);
        f32x4 s0[4], s1[4];
#pragma unroll
        for (int j = 0; j < 4; ++j)
#pragma unroll
            for (int reg = 0; reg < 4; ++reg) {
                s0[j][reg] = rh2f[reg]     + rwL[0][j][reg];
                s1[j][reg] = rh2f[4 + reg] + rwL[1][j][reg];
            }
        // S for both qgroups; kf read once, used twice
        __builtin_amdgcn_s_setprio(1);
#pragma unroll
        for (int s2 = 0; s2 < 2; ++s2) {
#pragma unroll
            for (int j = 0; j < 4; ++j) {
                bf16x8 kf = *(const bf16x8*)&skb[((s2 * 4 + quad) * 64 + j * 16 + r) * 8];
                s0[j] = __builtin_amdgcn_mfma_f32_16x16x32_bf16(qf[0][s2], kf, s0[j], 0, 0, 0);
                s1[j] = __builtin_amdgcn_mfma_f32_16x16x32_bf16(qf[1][s2], kf, s1[j], 0, 0, 0);
            }
        }
        __builtin_amdgcn_s_setprio(0);
        // softmax: bare v_exp_f32 (arg already = score*SC + bias, log2 units)
#pragma unroll
        for (int g = 0; g < 2; ++g) {
#pragma unroll
            for (int reg = 0; reg < 4; ++reg) {
                unsigned int u[4];
#pragma unroll
                for (int j = 0; j < 4; ++j) {
                    const float p = __builtin_amdgcn_exp2f(g ? s1[j][reg] : s0[j][reg]);
                    union { float f; unsigned int q; } cv; cv.f = p;
                    u[j] = cv.q;
                }
                u32x2 d;
                d.x = __builtin_amdgcn_perm(u[1], u[0], 0x07060302);
                d.y = __builtin_amdgcn_perm(u[3], u[2], 0x07060302);
                *(u32x2*)&spb[g * 4608 + w * 1152 + (quad * 4 + reg) * 72 + r * 4] = d;
            }
        }
        // PV: vf read once, used twice; l row-sum via ones-MFMA
        __builtin_amdgcn_s_setprio(1);
#pragma unroll
        for (int s = 0; s < 2; ++s) {
            bf16x8 pf0 = *(const bf16x8*)&spb[w * 1152 + r * 72 + s * 32 + quad * 8];
            bf16x8 pf1 = *(const bf16x8*)&spb[4608 + w * 1152 + r * 72 + s * 32 + quad * 8];
            lacc[0] = __builtin_amdgcn_mfma_f32_16x16x32_bf16(pf0, onesf, lacc[0], 0, 0, 0);
            lacc[1] = __builtin_amdgcn_mfma_f32_16x16x32_bf16(pf1, onesf, lacc[1], 0, 0, 0);
#pragma unroll
            for (int j = 0; j < 4; ++j) {
                bf16x8 vf = *(const bf16x8*)&svb[((s * 4 + quad) * 64 + j * 16 + r) * 8];
                oacc[0][j] = __builtin_amdgcn_mfma_f32_16x16x32_bf16(pf0, vf, oacc[0][j], 0, 0, 0);
                oacc[1][j] = __builtin_amdgcn_mfma_f32_16x16x32_bf16(pf1, vf, oacc[1][j], 0, 0, 0);
            }
        }
        __builtin_amdgcn_s_setprio(0);

        __syncthreads();             // skb/svb reads retired; vmcnt drain
                                     // covers loads issued a compute-phase ago
        if (tl < 15) {
            *(u32x4*)&skb[(w * 128 + lane) * 8]      = kp0;
            *(u32x4*)&skb[(w * 128 + 64 + lane) * 8] = kp1;
            *(u32x4*)&svb[(w * 128 + lane) * 8]      = vp0;
            *(u32x4*)&svb[(w * 128 + 64 + lane) * 8] = vp1;
        }
        __syncthreads();             // next tile visible (lgkm drain only)
    }
    // epilogue: store partials (lacc already holds full per-query row sums)
    const size_t pbase = ((size_t)(sp * 12 + h) * 4096 + qt * 128);
#pragma unroll
    for (int g = 0; g < 2; ++g) {
        const int qrow = g * 64 + w * 16 + quad * 4;
#pragma unroll
        for (int reg = 0; reg < 4; ++reg) {
#pragma unroll
            for (int j = 0; j < 4; ++j)
                po[(pbase + qrow + reg) * 64 + j * 16 + r] = oacc[g][j][reg];
            if (r == 0) lp[pbase + qrow + reg] = lacc[g][reg];
        }
    }
}

// ---------------------------------------------------------------------------
// Combine split-4 partials: ab[t][h*64+d] = (Σ po_s)/(Σ l_s) as bf16.
// ---------------------------------------------------------------------------
__global__ __launch_bounds__(256) void combine(const float* __restrict__ po,
                                               const float* __restrict__ lp,
                                               unsigned short* __restrict__ ab) {
    const unsigned int idx = blockIdx.x * 256 + threadIdx.x;  // 0..393215
    const unsigned int tok = idx / 96u;
    const unsigned int part = idx - tok * 96u;
    const int c = part * 8, h = c >> 6, d = c & 63;
    float lsum = 0.f;
    float acc0[4] = {0.f, 0.f, 0.f, 0.f}, acc1[4] = {0.f, 0.f, 0.f, 0.f};
#pragma unroll
    for (int s = 0; s < 4; ++s) {
        const float* p = po + (((size_t)(s * 12 + h)) * 4096 + tok) * 64 + d;
        const float4 a = *(const float4*)p, b = *(const float4*)(p + 4);
        acc0[0] += a.x; acc0[1] += a.y; acc0[2] += a.z; acc0[3] += a.w;
        acc1[0] += b.x; acc1[1] += b.y; acc1[2] += b.z; acc1[3] += b.w;
        lsum += lp[(size_t)(s * 12 + h) * 4096 + tok];
    }
    const float inv = 1.f / lsum;
    s16x4 o0, o1;
    o0[0] = (short)f2b(acc0[0] * inv); o0[1] = (short)f2b(acc0[1] * inv);
    o0[2] = (short)f2b(acc0[2] * inv); o0[3] = (short)f2b(acc0[3] * inv);
    o1[0] = (short)f2b(acc1[0] * inv); o1[1] = (short)f2b(acc1[1] * inv);
    o1[2] = (short)f2b(acc1[2] * inv); o1[3] = (short)f2b(acc1[3] * inv);
    unsigned short* dst = ab + (size_t)tok * 768 + c;
    *(s16x4*)dst = o0;
    *(s16x4*)(dst + 4) = o1;
}

// ---------------------------------------------------------------------------
extern "C" void kernel_launch(void* const* d_in, const int* in_sizes, int n_in,
                              void* d_out, int out_size, void* d_ws, size_t ws_size,
                              hipStream_t stream) {
    const float* hs  = (const float*)d_in[0];
    const float* wq  = (const float*)d_in[1];
    const float* bq  = (const float*)d_in[2];
    const float* wk  = (const float*)d_in[3];
    const float* bk  = (const float*)d_in[4];
    const float* wv  = (const float*)d_in[5];
    const float* bv  = (const float*)d_in[6];
    const float* wo  = (const float*)d_in[7];
    const float* bo  = (const float*)d_in[8];
    const float* rph = (const float*)d_in[9];
    const float* rpw = (const float*)d_in[10];

    unsigned short* ws = (unsigned short*)d_ws;
    const int HS = 3145728, WN = 589824, RP = 8128;
    const int HB = 12 * 4096 * 64;
    unsigned short* hsb  = ws;
    unsigned short* wqb  = hsb  + HS;
    unsigned short* wkb  = wqb  + WN;
    unsigned short* wvb  = wkb  + WN;
    unsigned short* wob  = wvb  + WN;
    unsigned short* rphb = wob  + WN;
    unsigned short* rpwb = rphb + RP;
    unsigned short* qb   = rpwb + RP;          // q*SC [h][t][d]
    unsigned short* kb   = qb   + HB;          // k    [h][t][d]
    unsigned short* vtb  = kb   + HB;          // v^T  [h][d][t], token-permuted
    unsigned short* rhb  = vtb  + HB;          // rel_h*log2e [h][t][ki]
    unsigned short* rwb  = rhb  + HB;          // rel_w*log2e [h][t][kj]
    unsigned short* ab   = rwb  + HB;          // attn out [t][768]
    float* po = (float*)(ab + HB);             // O_num partials [4][12][4096][64]
    float* lp = po + 4 * 12 * 4096 * 64;       // l partials [4][12][4096]

    cvt_bf16<<<dim3((1380320 + 255) / 256), 256, 0, stream>>>(
        hs, wq, wk, wv, wo, rph, rpw, hsb);
    qkv128<<<dim3(6, 32, 3), 256, 0, stream>>>(
        hsb, wqb, wkb, wvb, bq, bk, bv, qb, kb, vtb);
    relk<<<dim3(64, 12, 2), 256, 0, stream>>>(qb, rphb, rpwb, rhb, rwb);
    attn2<<<dim3(32, 12, 4), 256, 0, stream>>>(qb, kb, vtb, rhb, rwb, po, lp);
    combine<<<dim3(1536), 256, 0, stream>>>(po, lp, ab);
    out128<<<dim3(6, 32), 256, 0, stream>>>(ab, wob, bo, (float*)d_out);
}

// Round 7
// 234.320 us; speedup vs baseline: 1.6399x; 1.6399x over previous
//
#include <hip/hip_runtime.h>

// ---------------------------------------------------------------------------
// SAM vision attention (B=1, H=W=64, C=768, 12 heads x hd=64). fp32 I/O.
// cvt -> QKV proj (128-tile) -> rel_h/rel_w -> flash attn (split-K) ->
//   combine -> out proj
// MFMA v_mfma_f32_16x16x32_bf16 layouts (guide-verified m89/m91):
//   A/B frag: [m|n = lane&15][k = (lane>>4)*8 + j]   (8 bf16 / lane, b128)
//   C/D     : col = lane&15, row = (lane>>4)*4 + reg (4 f32 / lane)
// R16 = R15 split-4 with __launch_bounds__(256,3) (NOT 4).
// Post-mortem ledger:
//   R10 (78.5us): reg-staged K/V, srh LDS, 2 barriers/tile. Proven base.
//   R11 (90.9us): gl_lds dbuf single-barrier REGRESSED (m99/m100 repro).
//   R12 (90.3us): per-tile scalar rel_h globals stall barrier drains.
//   R13 (285us!): K/V in regs -> VGPR demand >> alloc -> scratch spill.
//   R14 (75.8us): R10 staging + math (Q pre-scale, bias-in-C, bare exp2). ✓
//   R15 (228us!): __launch_bounds__(256,4) stepped VGPR cap down to 64
//                 (occupancy tier, m69) -> ~20 reg spill -> FETCH 58->212MB.
//                 BUT occupancy did hit 32.7% (4 blk/CU resident).
//   R16: bounds arg is a MINIMUM for the allocator, not needed for occupancy.
//        (256,3) keeps R14's 84 VGPR (no spill); LDS 38912*4 = 155.6KB fits
//        160KB -> 4 blocks/CU via LDS math alone. Check: VGPR=84, WRITE=50MB.
// Math (validated R11/R12/R14): Q pre-scaled by SC=0.125*log2e in qkv;
// relk osc=8 so rhb/rwb hold rel*log2e; attn2 inits QK accumulator to rh+rw
// (bias-in-C); softmax is a bare v_exp_f32.
// ---------------------------------------------------------------------------

typedef __attribute__((ext_vector_type(8))) short bf16x8;
typedef __attribute__((ext_vector_type(4))) float f32x4;
typedef __attribute__((ext_vector_type(4))) short s16x4;
typedef __attribute__((ext_vector_type(2))) unsigned int u32x2;
typedef __attribute__((ext_vector_type(4))) unsigned int u32x4;

__device__ __forceinline__ float b2f(unsigned short h) {
    union { unsigned int u; float f; } v; v.u = ((unsigned int)h) << 16; return v.f;
}
__device__ __forceinline__ unsigned short f2b(float f) {
    union { float f; unsigned int u; } v; v.f = f;
    unsigned int r = v.u + 0x7FFFu + ((v.u >> 16) & 1u);  // RNE
    return (unsigned short)(r >> 16);
}
__device__ __forceinline__ void gl_lds16(const void* g, void* l) {
    __builtin_amdgcn_global_load_lds(
        (const __attribute__((address_space(1))) void*)g,
        (__attribute__((address_space(3))) void*)l, 16, 0, 0);
}

// ---------------------------------------------------------------------------
// fp32 -> bf16 bulk convert into one contiguous region (quad-indexed).
// ---------------------------------------------------------------------------
__global__ __launch_bounds__(256) void cvt_bf16(
        const float* __restrict__ hs, const float* __restrict__ wq,
        const float* __restrict__ wk, const float* __restrict__ wv,
        const float* __restrict__ wo, const float* __restrict__ rph,
        const float* __restrict__ rpw, unsigned short* __restrict__ dst) {
    const int idx = blockIdx.x * 256 + threadIdx.x;
    if (idx >= 1380320) return;
    const float* src;
    int off;
    if      (idx < 786432)  { src = hs;  off = idx; }
    else if (idx < 933888)  { src = wq;  off = idx - 786432; }
    else if (idx < 1081344) { src = wk;  off = idx - 933888; }
    else if (idx < 1228800) { src = wv;  off = idx - 1081344; }
    else if (idx < 1376256) { src = wo;  off = idx - 1228800; }
    else if (idx < 1378288) { src = rph; off = idx - 1376256; }
    else                    { src = rpw; off = idx - 1378288; }
    const float4 v = ((const float4*)src)[off];
    s16x4 o;
    o[0] = (short)f2b(v.x); o[1] = (short)f2b(v.y);
    o[2] = (short)f2b(v.z); o[3] = (short)f2b(v.w);
    *(s16x4*)(dst + (size_t)idx * 4) = o;
}

// ---------------------------------------------------------------------------
// Fused QKV projection, 128x128 tile. z: 0->q (PRE-SCALED by 0.125*log2e),
// 1->k [n>>6][m][n&63]; 2->v^T token-PERMUTED, stored via LDS transpose.
// K-loop: double-buffered gl_lds, one barrier per step.
// ---------------------------------------------------------------------------
__launch_bounds__(256, 3)
__global__ void qkv128(const unsigned short* __restrict__ X,
                       const unsigned short* __restrict__ Wq,
                       const unsigned short* __restrict__ Wk,
                       const unsigned short* __restrict__ Wv,
                       const float* __restrict__ bq,
                       const float* __restrict__ bk,
                       const float* __restrict__ bv,
                       unsigned short* __restrict__ qb,
                       unsigned short* __restrict__ kb,
                       unsigned short* __restrict__ vtb) {
    __shared__ __align__(16) unsigned short sarena[16384];  // 2 x (A 4096 + B 4096)
    const int tid = threadIdx.x, lane = tid & 63, w = tid >> 6;
    const int r = lane & 15, quad = lane >> 4;
    const int nt = blockIdx.x, mt = blockIdx.y, z = blockIdx.z;
    const unsigned short* W  = (z == 0) ? Wq : (z == 1) ? Wk : Wv;
    const float*          Bv = (z == 0) ? bq : (z == 1) ? bk : bv;
    unsigned short*     outp = (z == 0) ? qb : (z == 1) ? kb : vtb;
    const float qsc = (z == 0) ? 0.18033688f : 1.0f;  // 0.125*log2(e)

    const int c0 = w * 64 + lane, c1 = c0 + 256;
    const unsigned short* xs0 = X + (mt * 128 + (c0 & 127)) * 768 + (c0 >> 7) * 8;
    const unsigned short* xs1 = X + (mt * 128 + (c1 & 127)) * 768 + (c1 >> 7) * 8;
    const unsigned short* ws0 = W + (nt * 128 + (c0 & 127)) * 768 + (c0 >> 7) * 8;
    const unsigned short* ws1 = W + (nt * 128 + (c1 & 127)) * 768 + (c1 >> 7) * 8;

    // prologue: stage kt=0 into buffer 0
    gl_lds16(xs0, &sarena[w * 512]);
    gl_lds16(xs1, &sarena[2048 + w * 512]);
    gl_lds16(ws0, &sarena[4096 + w * 512]);
    gl_lds16(ws1, &sarena[4096 + 2048 + w * 512]);
    __syncthreads();

    const int wr = (w & 1) * 64, wc = (w >> 1) * 64;
    f32x4 acc[4][4] = {};
    int cur = 0;
#pragma unroll 2
    for (int kt = 0; kt < 24; ++kt) {
        if (kt < 23) {              // issue next K-step into alt buffer
            const int nx = (cur ^ 1) * 8192;
            gl_lds16(xs0 + (kt + 1) * 32, &sarena[nx + w * 512]);
            gl_lds16(xs1 + (kt + 1) * 32, &sarena[nx + 2048 + w * 512]);
            gl_lds16(ws0 + (kt + 1) * 32, &sarena[nx + 4096 + w * 512]);
            gl_lds16(ws1 + (kt + 1) * 32, &sarena[nx + 4096 + 2048 + w * 512]);
        }
        const unsigned short* ab = &sarena[cur * 8192];
        const unsigned short* bb = ab + 4096;
        bf16x8 af[4], bfr[4];
#pragma unroll
        for (int i = 0; i < 4; ++i)
            af[i] = *(const bf16x8*)&ab[(quad * 128 + wr + i * 16 + r) * 8];
#pragma unroll
        for (int j = 0; j < 4; ++j)
            bfr[j] = *(const bf16x8*)&bb[(quad * 128 + wc + j * 16 + r) * 8];
#pragma unroll
        for (int i = 0; i < 4; ++i)
#pragma unroll
            for (int j = 0; j < 4; ++j)
                acc[i][j] = __builtin_amdgcn_mfma_f32_16x16x32_bf16(af[i], bfr[j], acc[i][j], 0, 0, 0);
        __syncthreads();            // drains vmcnt(0): next tile landed+visible
        cur ^= 1;
    }
    if (z < 2) {
#pragma unroll
        for (int j = 0; j < 4; ++j) {
            const int n = nt * 128 + wc + j * 16 + r;
            const float bias = Bv[n];
            const int nhi = n >> 6, nlo = n & 63;
#pragma unroll
            for (int i = 0; i < 4; ++i) {
#pragma unroll
                for (int reg = 0; reg < 4; ++reg) {
                    const int m = mt * 128 + wr + i * 16 + quad * 4 + reg;
                    outp[(nhi * 4096 + m) * 64 + nlo] = f2b((acc[i][j][reg] + bias) * qsc);
                }
            }
        }
    } else {
#pragma unroll
        for (int pass = 0; pass < 2; ++pass) {
            if ((w >> 1) == pass) {
#pragma unroll
                for (int j = 0; j < 4; ++j) {
                    const int n_l = j * 16 + r;
                    const float bias = Bv[nt * 128 + pass * 64 + n_l];
                    const int sw = (n_l & 7) << 4;
#pragma unroll
                    for (int reg = 0; reg < 4; ++reg) {
                        const int tokb = (wr + (quad * 4 + reg) * 4) ^ sw;
                        u32x2 d2;
                        d2.x = (unsigned int)f2b(acc[0][j][reg] + bias)
                             | ((unsigned int)f2b(acc[1][j][reg] + bias) << 16);
                        d2.y = (unsigned int)f2b(acc[2][j][reg] + bias)
                             | ((unsigned int)f2b(acc[3][j][reg] + bias) << 16);
                        *(u32x2*)&sarena[n_l * 128 + tokb] = d2;
                    }
                }
            }
            __syncthreads();
#pragma unroll
            for (int c = 0; c < 4; ++c) {
                const int u = c * 256 + tid;
                const int n_l = u >> 4, g = u & 15;
                const int phys = n_l * 128 + ((g * 8) ^ ((n_l & 7) << 4));
                bf16x8 val = *(const bf16x8*)&sarena[phys];
                *(bf16x8*)&outp[(size_t)(nt * 128 + pass * 64 + n_l) * 4096
                                + mt * 128 + g * 8] = val;
            }
            __syncthreads();
        }
    }
}

// ---------------------------------------------------------------------------
// Output projection, 128x128 tile, fp32 row-major out. Same dbuf K-loop.
// ---------------------------------------------------------------------------
__launch_bounds__(256, 3)
__global__ void out128(const unsigned short* __restrict__ X,
                       const unsigned short* __restrict__ W,
                       const float* __restrict__ Bv,
                       float* __restrict__ out) {
    __shared__ __align__(16) unsigned short sarena[16384];
    const int tid = threadIdx.x, lane = tid & 63, w = tid >> 6;
    const int r = lane & 15, quad = lane >> 4;
    const int nt = blockIdx.x, mt = blockIdx.y;

    const int c0 = w * 64 + lane, c1 = c0 + 256;
    const unsigned short* xs0 = X + (mt * 128 + (c0 & 127)) * 768 + (c0 >> 7) * 8;
    const unsigned short* xs1 = X + (mt * 128 + (c1 & 127)) * 768 + (c1 >> 7) * 8;
    const unsigned short* ws0 = W + (nt * 128 + (c0 & 127)) * 768 + (c0 >> 7) * 8;
    const unsigned short* ws1 = W + (nt * 128 + (c1 & 127)) * 768 + (c1 >> 7) * 8;

    gl_lds16(xs0, &sarena[w * 512]);
    gl_lds16(xs1, &sarena[2048 + w * 512]);
    gl_lds16(ws0, &sarena[4096 + w * 512]);
    gl_lds16(ws1, &sarena[4096 + 2048 + w * 512]);
    __syncthreads();

    const int wr = (w & 1) * 64, wc = (w >> 1) * 64;
    f32x4 acc[4][4] = {};
    int cur = 0;
#pragma unroll 2
    for (int kt = 0; kt < 24; ++kt) {
        if (kt < 23) {
            const int nx = (cur ^ 1) * 8192;
            gl_lds16(xs0 + (kt + 1) * 32, &sarena[nx + w * 512]);
            gl_lds16(xs1 + (kt + 1) * 32, &sarena[nx + 2048 + w * 512]);
            gl_lds16(ws0 + (kt + 1) * 32, &sarena[nx + 4096 + w * 512]);
            gl_lds16(ws1 + (kt + 1) * 32, &sarena[nx + 4096 + 2048 + w * 512]);
        }
        const unsigned short* ab = &sarena[cur * 8192];
        const unsigned short* bb = ab + 4096;
        bf16x8 af[4], bfr[4];
#pragma unroll
        for (int i = 0; i < 4; ++i)
            af[i] = *(const bf16x8*)&ab[(quad * 128 + wr + i * 16 + r) * 8];
#pragma unroll
        for (int j = 0; j < 4; ++j)
            bfr[j] = *(const bf16x8*)&bb[(quad * 128 + wc + j * 16 + r) * 8];
#pragma unroll
        for (int i = 0; i < 4; ++i)
#pragma unroll
            for (int j = 0; j < 4; ++j)
                acc[i][j] = __builtin_amdgcn_mfma_f32_16x16x32_bf16(af[i], bfr[j], acc[i][j], 0, 0, 0);
        __syncthreads();
        cur ^= 1;
    }
#pragma unroll
    for (int j = 0; j < 4; ++j) {
        const int n = nt * 128 + wc + j * 16 + r;
        const float bias = Bv[n];
#pragma unroll
        for (int i = 0; i < 4; ++i) {
#pragma unroll
            for (int reg = 0; reg < 4; ++reg) {
                const int m = mt * 128 + wr + i * 16 + quad * 4 + reg;
                out[m * 768 + n] = acc[i][j][reg] + bias;
            }
        }
    }
}

// ---------------------------------------------------------------------------
// rel_h / rel_w: per (head, a) 64x64x64 GEMM against gathered rel_pos rows.
// q is pre-scaled by SC=0.125*log2e, so osc=8 yields rel*log2e for BOTH modes.
// ---------------------------------------------------------------------------
__launch_bounds__(256, 4)
__global__ void relk(const unsigned short* __restrict__ qbuf,
                     const unsigned short* __restrict__ rph,
                     const unsigned short* __restrict__ rpw,
                     unsigned short* __restrict__ rh,
                     unsigned short* __restrict__ rw) {
    __shared__ __align__(16) unsigned short abuf[8 * 64 * 8];
    __shared__ __align__(16) unsigned short bbuf[8 * 64 * 8];
    const int tid = threadIdx.x;
    const int lane = tid & 63, w = tid >> 6;
    const int r = lane & 15, quad = lane >> 4;
    const int a = blockIdx.x, h = blockIdx.y, mode = blockIdx.z;
    const unsigned short* rp = mode ? rpw : rph;
    const float osc = 8.0f;  // log2e / SC

#pragma unroll
    for (int gg = 0; gg < 2; ++gg) {
        const int g = w * 2 + gg;
        const int arow = mode ? (h * 4096 + lane * 64 + a) : (h * 4096 + a * 64 + lane);
        gl_lds16(qbuf + arow * 64 + g * 8, &abuf[g * 512]);
        const int bidx = a - lane + 63;
        gl_lds16(rp + bidx * 64 + g * 8, &bbuf[g * 512]);
    }
    __syncthreads();

    f32x4 acc[4] = {};
#pragma unroll
    for (int s = 0; s < 2; ++s) {
        bf16x8 af = *(const bf16x8*)&abuf[((s * 4 + quad) * 64 + w * 16 + r) * 8];
#pragma unroll
        for (int j = 0; j < 4; ++j) {
            bf16x8 bfr = *(const bf16x8*)&bbuf[((s * 4 + quad) * 64 + j * 16 + r) * 8];
            acc[j] = __builtin_amdgcn_mfma_f32_16x16x32_bf16(af, bfr, acc[j], 0, 0, 0);
        }
    }
    unsigned short* out = mode ? rw : rh;
#pragma unroll
    for (int j = 0; j < 4; ++j) {
#pragma unroll
        for (int reg = 0; reg < 4; ++reg) {
            const int m = w * 16 + quad * 4 + reg, n = j * 16 + r;
            const int t = mode ? (h * 4096 + m * 64 + a) : (h * 4096 + a * 64 + m);
            out[t * 64 + n] = f2b(acc[j][reg] * osc);
        }
    }
}

// ---------------------------------------------------------------------------
// Flash attention, SPLIT-4: block = 128-query tile (2 qgroups of 16 / wave),
// split sp covers key tiles sp*16..sp*16+15.
// Fixed softmax ref (m=0). Per-tile structure (R14-proven):
//   issue global_load_dwordx4 (K,V tile t+1 -> 16 staging VGPRs)
//   rh2 <- srh LDS; acc init = rh2+rwL (bias-in-C)
//   -> QK MFMA -> bare v_exp_f32 + pack -> PV MFMA (+ ones-MFMA row-sum l)
//   barrier (vmcnt drain covers loads issued a phase ago)
//   ds_write K/V regs -> LDS ; barrier.
// LDS 38912 B -> 4 blocks/CU by LDS math; __launch_bounds__ stays (256,3)
// so the allocator keeps R14's 84 VGPR (R15: bound=4 stepped cap to 64 ->
// spill; bounds arg is a minimum guarantee, not an occupancy requirement).
// ---------------------------------------------------------------------------
__launch_bounds__(256, 3)
__global__ void attn2(const unsigned short* __restrict__ qbuf,
                      const unsigned short* __restrict__ kbuf,
                      const unsigned short* __restrict__ vtbuf,
                      const unsigned short* __restrict__ rhb,
                      const unsigned short* __restrict__ rwb,
                      float* __restrict__ po, float* __restrict__ lp) {
    __shared__ __align__(16) unsigned short skb[4096];   // K [d_oct][key][8]
    __shared__ __align__(16) unsigned short svb[4096];   // V^T [scol_oct][d][8]
    __shared__ __align__(16) unsigned short spb[9216];   // P x2 groups, stride 72
    __shared__ __align__(16) unsigned short srh[2048];   // rel_h*L2E, split's 2 octs
    const int tid = threadIdx.x;
    const int lane = tid & 63, w = tid >> 6;
    const int r = lane & 15, quad = lane >> 4;
    const int qt = blockIdx.x, h = blockIdx.y, sp = blockIdx.z;

    // srh: rel_h*log2e, this split's 2 ki-octs (ki = sp*16 .. sp*16+15)
    {
        const int ql = (w & 1) * 64 + lane;
        gl_lds16(rhb + (h * 4096 + qt * 128 + ql) * 64 + (sp * 2 + (w >> 1)) * 8,
                 &srh[w * 512]);
    }
    // per-thread K/V staging sources (16B per lane per oct; octs w*2, w*2+1)
    const unsigned short* ksrc = kbuf + (size_t)(h * 4096 + lane) * 64 + w * 16;
    const unsigned short* vsrc = vtbuf + (size_t)(h * 64 + lane) * 4096 + w * 16;
    u32x4 kp0, kp1, vp0, vp1;
    {
        const int t0 = sp * 16;
        kp0 = *(const u32x4*)(ksrc + (size_t)t0 * 4096);
        kp1 = *(const u32x4*)(ksrc + (size_t)t0 * 4096 + 8);
        vp0 = *(const u32x4*)(vsrc + t0 * 64);
        vp1 = *(const u32x4*)(vsrc + t0 * 64 + 8);
    }
    bf16x8 qf[2][2];
#pragma unroll
    for (int g = 0; g < 2; ++g) {
        const unsigned short* qrow =
            qbuf + (h * 4096 + qt * 128 + g * 64 + w * 16 + r) * 64;
        qf[g][0] = *(const bf16x8*)(qrow + quad * 8);
        qf[g][1] = *(const bf16x8*)(qrow + 32 + quad * 8);
    }
    float rwL[2][4][4];
#pragma unroll
    for (int g = 0; g < 2; ++g) {
        const unsigned short* rwrow = rwb + (h * 4096 + qt * 128 + g * 64) * 64;
#pragma unroll
        for (int reg = 0; reg < 4; ++reg) {
            const int ql = w * 16 + quad * 4 + reg;
#pragma unroll
            for (int j = 0; j < 4; ++j)
                rwL[g][j][reg] = b2f(rwrow[ql * 64 + j * 16 + r]);  // already *log2e
        }
    }
    bf16x8 onesf;
#pragma unroll
    for (int i = 0; i < 8; ++i) onesf[i] = (short)0x3F80;  // bf16 1.0

    f32x4 lacc[2] = {};
    f32x4 oacc[2][4] = {};
    __syncthreads();                 // srh staged + tile-0 loads complete
    *(u32x4*)&skb[(w * 128 + lane) * 8]      = kp0;
    *(u32x4*)&skb[(w * 128 + 64 + lane) * 8] = kp1;
    *(u32x4*)&svb[(w * 128 + lane) * 8]      = vp0;
    *(u32x4*)&svb[(w * 128 + 64 + lane) * 8] = vp1;
    __syncthreads();                 // tile-0 visible

    for (int tl = 0; tl < 16; ++tl) {
        const int t = sp * 16 + tl;
        if (tl < 15) {               // issue next-tile loads (awaited at barrier1)
            kp0 = *(const u32x4*)(ksrc + (size_t)(t + 1) * 4096);
            kp1 = *(const u32x4*)(ksrc + (size_t)(t + 1) * 4096 + 8);
            vp0 = *(const u32x4*)(vsrc + (t + 1) * 64);
            vp1 = *(const u32x4*)(vsrc + (t + 1) * 64 + 8);
        }
        // bias-in-C: acc starts at rh+rw (both already in log2 units)
        float rh2f[8];
#pragma unroll
        for (int i = 0; i < 8; ++i)
            rh2f[i] = b2f(srh[((tl >> 3) * 128 + (i >> 2) * 64 + w * 16
                               + quad * 4 + (i & 3)) * 8 + (t & 7)]);
        f32x4 s0[4], s1[4];
#pragma unroll
        for (int j = 0; j < 4; ++j)
#pragma unroll
            for (int reg = 0; reg < 4; ++reg) {
                s0[j][reg] = rh2f[reg]     + rwL[0][j][reg];
                s1[j][reg] = rh2f[4 + reg] + rwL[1][j][reg];
            }
        // S for both qgroups; kf read once, used twice
        __builtin_amdgcn_s_setprio(1);
#pragma unroll
        for (int s2 = 0; s2 < 2; ++s2) {
#pragma unroll
            for (int j = 0; j < 4; ++j) {
                bf16x8 kf = *(const bf16x8*)&skb[((s2 * 4 + quad) * 64 + j * 16 + r) * 8];
                s0[j] = __builtin_amdgcn_mfma_f32_16x16x32_bf16(qf[0][s2], kf, s0[j], 0, 0, 0);
                s1[j] = __builtin_amdgcn_mfma_f32_16x16x32_bf16(qf[1][s2], kf, s1[j], 0, 0, 0);
            }
        }
        __builtin_amdgcn_s_setprio(0);
        // softmax: bare v_exp_f32 (arg already = score*SC + bias, log2 units)
#pragma unroll
        for (int g = 0; g < 2; ++g) {
#pragma unroll
            for (int reg = 0; reg < 4; ++reg) {
                unsigned int u[4];
#pragma unroll
                for (int j = 0; j < 4; ++j) {
                    const float p = __builtin_amdgcn_exp2f(g ? s1[j][reg] : s0[j][reg]);
                    union { float f; unsigned int q; } cv; cv.f = p;
                    u[j] = cv.q;
                }
                u32x2 d;
                d.x = __builtin_amdgcn_perm(u[1], u[0], 0x07060302);
                d.y = __builtin_amdgcn_perm(u[3], u[2], 0x07060302);
                *(u32x2*)&spb[g * 4608 + w * 1152 + (quad * 4 + reg) * 72 + r * 4] = d;
            }
        }
        // PV: vf read once, used twice; l row-sum via ones-MFMA
        __builtin_amdgcn_s_setprio(1);
#pragma unroll
        for (int s = 0; s < 2; ++s) {
            bf16x8 pf0 = *(const bf16x8*)&spb[w * 1152 + r * 72 + s * 32 + quad * 8];
            bf16x8 pf1 = *(const bf16x8*)&spb[4608 + w * 1152 + r * 72 + s * 32 + quad * 8];
            lacc[0] = __builtin_amdgcn_mfma_f32_16x16x32_bf16(pf0, onesf, lacc[0], 0, 0, 0);
            lacc[1] = __builtin_amdgcn_mfma_f32_16x16x32_bf16(pf1, onesf, lacc[1], 0, 0, 0);
#pragma unroll
            for (int j = 0; j < 4; ++j) {
                bf16x8 vf = *(const bf16x8*)&svb[((s * 4 + quad) * 64 + j * 16 + r) * 8];
                oacc[0][j] = __builtin_amdgcn_mfma_f32_16x16x32_bf16(pf0, vf, oacc[0][j], 0, 0, 0);
                oacc[1][j] = __builtin_amdgcn_mfma_f32_16x16x32_bf16(pf1, vf, oacc[1][j], 0, 0, 0);
            }
        }
        __builtin_amdgcn_s_setprio(0);

        __syncthreads();             // skb/svb reads retired; vmcnt drain
                                     // covers loads issued a compute-phase ago
        if (tl < 15) {
            *(u32x4*)&skb[(w * 128 + lane) * 8]      = kp0;
            *(u32x4*)&skb[(w * 128 + 64 + lane) * 8] = kp1;
            *(u32x4*)&svb[(w * 128 + lane) * 8]      = vp0;
            *(u32x4*)&svb[(w * 128 + 64 + lane) * 8] = vp1;
        }
        __syncthreads();             // next tile visible (lgkm drain only)
    }
    // epilogue: store partials (lacc already holds full per-query row sums)
    const size_t pbase = ((size_t)(sp * 12 + h) * 4096 + qt * 128);
#pragma unroll
    for (int g = 0; g < 2; ++g) {
        const int qrow = g * 64 + w * 16 + quad * 4;
#pragma unroll
        for (int reg = 0; reg < 4; ++reg) {
#pragma unroll
            for (int j = 0; j < 4; ++j)
                po[(pbase + qrow + reg) * 64 + j * 16 + r] = oacc[g][j][reg];
            if (r == 0) lp[pbase + qrow + reg] = lacc[g][reg];
        }
    }
}

// ---------------------------------------------------------------------------
// Combine split-4 partials: ab[t][h*64+d] = (Σ po_s)/(Σ l_s) as bf16.
// ---------------------------------------------------------------------------
__global__ __launch_bounds__(256) void combine(const float* __restrict__ po,
                                               const float* __restrict__ lp,
                                               unsigned short* __restrict__ ab) {
    const unsigned int idx = blockIdx.x * 256 + threadIdx.x;  // 0..393215
    const unsigned int tok = idx / 96u;
    const unsigned int part = idx - tok * 96u;
    const int c = part * 8, h = c >> 6, d = c & 63;
    float lsum = 0.f;
    float acc0[4] = {0.f, 0.f, 0.f, 0.f}, acc1[4] = {0.f, 0.f, 0.f, 0.f};
#pragma unroll
    for (int s = 0; s < 4; ++s) {
        const float* p = po + (((size_t)(s * 12 + h)) * 4096 + tok) * 64 + d;
        const float4 a = *(const float4*)p, b = *(const float4*)(p + 4);
        acc0[0] += a.x; acc0[1] += a.y; acc0[2] += a.z; acc0[3] += a.w;
        acc1[0] += b.x; acc1[1] += b.y; acc1[2] += b.z; acc1[3] += b.w;
        lsum += lp[(size_t)(s * 12 + h) * 4096 + tok];
    }
    const float inv = 1.f / lsum;
    s16x4 o0, o1;
    o0[0] = (short)f2b(acc0[0] * inv); o0[1] = (short)f2b(acc0[1] * inv);
    o0[2] = (short)f2b(acc0[2] * inv); o0[3] = (short)f2b(acc0[3] * inv);
    o1[0] = (short)f2b(acc1[0] * inv); o1[1] = (short)f2b(acc1[1] * inv);
    o1[2] = (short)f2b(acc1[2] * inv); o1[3] = (short)f2b(acc1[3] * inv);
    unsigned short* dst = ab + (size_t)tok * 768 + c;
    *(s16x4*)dst = o0;
    *(s16x4*)(dst + 4) = o1;
}

// ---------------------------------------------------------------------------
extern "C" void kernel_launch(void* const* d_in, const int* in_sizes, int n_in,
                              void* d_out, int out_size, void* d_ws, size_t ws_size,
                              hipStream_t stream) {
    const float* hs  = (const float*)d_in[0];
    const float* wq  = (const float*)d_in[1];
    const float* bq  = (const float*)d_in[2];
    const float* wk  = (const float*)d_in[3];
    const float* bk  = (const float*)d_in[4];
    const float* wv  = (const float*)d_in[5];
    const float* bv  = (const float*)d_in[6];
    const float* wo  = (const float*)d_in[7];
    const float* bo  = (const float*)d_in[8];
    const float* rph = (const float*)d_in[9];
    const float* rpw = (const float*)d_in[10];

    unsigned short* ws = (unsigned short*)d_ws;
    const int HS = 3145728, WN = 589824, RP = 8128;
    const int HB = 12 * 4096 * 64;
    unsigned short* hsb  = ws;
    unsigned short* wqb  = hsb  + HS;
    unsigned short* wkb  = wqb  + WN;
    unsigned short* wvb  = wkb  + WN;
    unsigned short* wob  = wvb  + WN;
    unsigned short* rphb = wob  + WN;
    unsigned short* rpwb = rphb + RP;
    unsigned short* qb   = rpwb + RP;          // q*SC [h][t][d]
    unsigned short* kb   = qb   + HB;          // k    [h][t][d]
    unsigned short* vtb  = kb   + HB;          // v^T  [h][d][t], token-permuted
    unsigned short* rhb  = vtb  + HB;          // rel_h*log2e [h][t][ki]
    unsigned short* rwb  = rhb  + HB;          // rel_w*log2e [h][t][kj]
    unsigned short* ab   = rwb  + HB;          // attn out [t][768]
    float* po = (float*)(ab + HB);             // O_num partials [4][12][4096][64]
    float* lp = po + 4 * 12 * 4096 * 64;       // l partials [4][12][4096]

    cvt_bf16<<<dim3((1380320 + 255) / 256), 256, 0, stream>>>(
        hs, wq, wk, wv, wo, rph, rpw, hsb);
    qkv128<<<dim3(6, 32, 3), 256, 0, stream>>>(
        hsb, wqb, wkb, wvb, bq, bk, bv, qb, kb, vtb);
    relk<<<dim3(64, 12, 2), 256, 0, stream>>>(qb, rphb, rpwb, rhb, rwb);
    attn2<<<dim3(32, 12, 4), 256, 0, stream>>>(qb, kb, vtb, rhb, rwb, po, lp);
    combine<<<dim3(1536), 256, 0, stream>>>(po, lp, ab);
    out128<<<dim3(6, 32), 256, 0, stream>>>(ab, wob, bo, (float*)d_out);
}

// Round 8
// 225.910 us; speedup vs baseline: 1.7010x; 1.0372x over previous
//
#include <hip/hip_runtime.h>

// ---------------------------------------------------------------------------
// SAM vision attention (B=1, H=W=64, C=768, 12 heads x hd=64). fp32 I/O.
// cvt -> QKV proj (128-tile) -> rel_h/rel_w -> flash attn (split-2, 32 q/wave)
//   -> combine -> out proj
// MFMA v_mfma_f32_16x16x32_bf16 layouts (guide-verified m89/m91):
//   A/B frag: [m|n = lane&15][k = (lane>>4)*8 + j]   (8 bf16 / lane, b128)
//   C/D     : col = lane&15, row = (lane>>4)*4 + reg (4 f32 / lane)
// R17 = R14 exact (proven 229.0us total, attn2 75.8us) + chunked XCD swizzle
// (T1) on qkv128/out128 grids.
// Post-mortem ledger:
//   R10 (78.5us): reg-staged K/V, srh LDS, 2 barriers/tile. Proven base.
//   R11 (90.9us): gl_lds dbuf single-barrier REGRESSED (m99/m100 repro).
//   R12 (90.3us): per-tile scalar rel_h globals stall barrier drains.
//   R13 (285us!): K/V in regs -> VGPR demand >> alloc -> scratch spill.
//   R14 (75.8us): R10 staging + math (Q pre-scale, bias-in-C, bare exp2). ✓
//   R15 (228us!): __launch_bounds__(256,4) stepped VGPR cap to 64 -> spill.
//   R16 (78.2us): split-4 @ (256,3): clean (VGPR 84, no spill) but occupancy
//                 STAYED 26.8% and prologue/FETCH costs doubled. Occupancy
//                 lever on attn2 is tested-and-dead; stall is barrier-
//                 structural. Revert to split-2.
// Swizzle mechanism: qkv/out grids have nt fastest -> 6 consecutive blocks
// share one 196KB X/ab row-panel but land on 6 different XCDs (round-robin).
// work=(lin%8)*chunk+lin/8 gives each XCD contiguous panels -> panel re-reads
// hit own-XCD L2. 576%8==0, 192%8==0 -> bijective (ERRATA #11 ok).
// Math (validated R11/R12/R14): Q pre-scaled by SC=0.125*log2e in qkv;
// relk osc=8 so rhb/rwb hold rel*log2e; attn2 inits QK accumulator to rh+rw
// (bias-in-C); softmax is a bare v_exp_f32.
// ---------------------------------------------------------------------------

typedef __attribute__((ext_vector_type(8))) short bf16x8;
typedef __attribute__((ext_vector_type(4))) float f32x4;
typedef __attribute__((ext_vector_type(4))) short s16x4;
typedef __attribute__((ext_vector_type(2))) unsigned int u32x2;
typedef __attribute__((ext_vector_type(4))) unsigned int u32x4;

__device__ __forceinline__ float b2f(unsigned short h) {
    union { unsigned int u; float f; } v; v.u = ((unsigned int)h) << 16; return v.f;
}
__device__ __forceinline__ unsigned short f2b(float f) {
    union { float f; unsigned int u; } v; v.f = f;
    unsigned int r = v.u + 0x7FFFu + ((v.u >> 16) & 1u);  // RNE
    return (unsigned short)(r >> 16);
}
__device__ __forceinline__ void gl_lds16(const void* g, void* l) {
    __builtin_amdgcn_global_load_lds(
        (const __attribute__((address_space(1))) void*)g,
        (__attribute__((address_space(3))) void*)l, 16, 0, 0);
}

// ---------------------------------------------------------------------------
// fp32 -> bf16 bulk convert into one contiguous region (quad-indexed).
// ---------------------------------------------------------------------------
__global__ __launch_bounds__(256) void cvt_bf16(
        const float* __restrict__ hs, const float* __restrict__ wq,
        const float* __restrict__ wk, const float* __restrict__ wv,
        const float* __restrict__ wo, const float* __restrict__ rph,
        const float* __restrict__ rpw, unsigned short* __restrict__ dst) {
    const int idx = blockIdx.x * 256 + threadIdx.x;
    if (idx >= 1380320) return;
    const float* src;
    int off;
    if      (idx < 786432)  { src = hs;  off = idx; }
    else if (idx < 933888)  { src = wq;  off = idx - 786432; }
    else if (idx < 1081344) { src = wk;  off = idx - 933888; }
    else if (idx < 1228800) { src = wv;  off = idx - 1081344; }
    else if (idx < 1376256) { src = wo;  off = idx - 1228800; }
    else if (idx < 1378288) { src = rph; off = idx - 1376256; }
    else                    { src = rpw; off = idx - 1378288; }
    const float4 v = ((const float4*)src)[off];
    s16x4 o;
    o[0] = (short)f2b(v.x); o[1] = (short)f2b(v.y);
    o[2] = (short)f2b(v.z); o[3] = (short)f2b(v.w);
    *(s16x4*)(dst + (size_t)idx * 4) = o;
}

// ---------------------------------------------------------------------------
// Fused QKV projection, 128x128 tile. z: 0->q (PRE-SCALED by 0.125*log2e),
// 1->k [n>>6][m][n&63]; 2->v^T token-PERMUTED, stored via LDS transpose.
// K-loop: double-buffered gl_lds, one barrier per step.
// Grid: 1D 576, XCD-chunk-swizzled (chunk = 576/8 = 72).
// ---------------------------------------------------------------------------
__launch_bounds__(256, 3)
__global__ void qkv128(const unsigned short* __restrict__ X,
                       const unsigned short* __restrict__ Wq,
                       const unsigned short* __restrict__ Wk,
                       const unsigned short* __restrict__ Wv,
                       const float* __restrict__ bq,
                       const float* __restrict__ bk,
                       const float* __restrict__ bv,
                       unsigned short* __restrict__ qb,
                       unsigned short* __restrict__ kb,
                       unsigned short* __restrict__ vtb) {
    __shared__ __align__(16) unsigned short sarena[16384];  // 2 x (A 4096 + B 4096)
    const int tid = threadIdx.x, lane = tid & 63, w = tid >> 6;
    const int r = lane & 15, quad = lane >> 4;
    // XCD chunked swizzle: lin%8 = XCD -> give it works [x*72, x*72+72)
    const int lin = blockIdx.x;                 // 0..575
    const int wk576 = (lin & 7) * 72 + (lin >> 3);
    const int nt = wk576 % 6, mt = (wk576 / 6) & 31, z = wk576 / 192;
    const unsigned short* W  = (z == 0) ? Wq : (z == 1) ? Wk : Wv;
    const float*          Bv = (z == 0) ? bq : (z == 1) ? bk : bv;
    unsigned short*     outp = (z == 0) ? qb : (z == 1) ? kb : vtb;
    const float qsc = (z == 0) ? 0.18033688f : 1.0f;  // 0.125*log2(e)

    const int c0 = w * 64 + lane, c1 = c0 + 256;
    const unsigned short* xs0 = X + (mt * 128 + (c0 & 127)) * 768 + (c0 >> 7) * 8;
    const unsigned short* xs1 = X + (mt * 128 + (c1 & 127)) * 768 + (c1 >> 7) * 8;
    const unsigned short* ws0 = W + (nt * 128 + (c0 & 127)) * 768 + (c0 >> 7) * 8;
    const unsigned short* ws1 = W + (nt * 128 + (c1 & 127)) * 768 + (c1 >> 7) * 8;

    // prologue: stage kt=0 into buffer 0
    gl_lds16(xs0, &sarena[w * 512]);
    gl_lds16(xs1, &sarena[2048 + w * 512]);
    gl_lds16(ws0, &sarena[4096 + w * 512]);
    gl_lds16(ws1, &sarena[4096 + 2048 + w * 512]);
    __syncthreads();

    const int wr = (w & 1) * 64, wc = (w >> 1) * 64;
    f32x4 acc[4][4] = {};
    int cur = 0;
#pragma unroll 2
    for (int kt = 0; kt < 24; ++kt) {
        if (kt < 23) {              // issue next K-step into alt buffer
            const int nx = (cur ^ 1) * 8192;
            gl_lds16(xs0 + (kt + 1) * 32, &sarena[nx + w * 512]);
            gl_lds16(xs1 + (kt + 1) * 32, &sarena[nx + 2048 + w * 512]);
            gl_lds16(ws0 + (kt + 1) * 32, &sarena[nx + 4096 + w * 512]);
            gl_lds16(ws1 + (kt + 1) * 32, &sarena[nx + 4096 + 2048 + w * 512]);
        }
        const unsigned short* ab = &sarena[cur * 8192];
        const unsigned short* bb = ab + 4096;
        bf16x8 af[4], bfr[4];
#pragma unroll
        for (int i = 0; i < 4; ++i)
            af[i] = *(const bf16x8*)&ab[(quad * 128 + wr + i * 16 + r) * 8];
#pragma unroll
        for (int j = 0; j < 4; ++j)
            bfr[j] = *(const bf16x8*)&bb[(quad * 128 + wc + j * 16 + r) * 8];
#pragma unroll
        for (int i = 0; i < 4; ++i)
#pragma unroll
            for (int j = 0; j < 4; ++j)
                acc[i][j] = __builtin_amdgcn_mfma_f32_16x16x32_bf16(af[i], bfr[j], acc[i][j], 0, 0, 0);
        __syncthreads();            // drains vmcnt(0): next tile landed+visible
        cur ^= 1;
    }
    if (z < 2) {
#pragma unroll
        for (int j = 0; j < 4; ++j) {
            const int n = nt * 128 + wc + j * 16 + r;
            const float bias = Bv[n];
            const int nhi = n >> 6, nlo = n & 63;
#pragma unroll
            for (int i = 0; i < 4; ++i) {
#pragma unroll
                for (int reg = 0; reg < 4; ++reg) {
                    const int m = mt * 128 + wr + i * 16 + quad * 4 + reg;
                    outp[(nhi * 4096 + m) * 64 + nlo] = f2b((acc[i][j][reg] + bias) * qsc);
                }
            }
        }
    } else {
#pragma unroll
        for (int pass = 0; pass < 2; ++pass) {
            if ((w >> 1) == pass) {
#pragma unroll
                for (int j = 0; j < 4; ++j) {
                    const int n_l = j * 16 + r;
                    const float bias = Bv[nt * 128 + pass * 64 + n_l];
                    const int sw = (n_l & 7) << 4;
#pragma unroll
                    for (int reg = 0; reg < 4; ++reg) {
                        const int tokb = (wr + (quad * 4 + reg) * 4) ^ sw;
                        u32x2 d2;
                        d2.x = (unsigned int)f2b(acc[0][j][reg] + bias)
                             | ((unsigned int)f2b(acc[1][j][reg] + bias) << 16);
                        d2.y = (unsigned int)f2b(acc[2][j][reg] + bias)
                             | ((unsigned int)f2b(acc[3][j][reg] + bias) << 16);
                        *(u32x2*)&sarena[n_l * 128 + tokb] = d2;
                    }
                }
            }
            __syncthreads();
#pragma unroll
            for (int c = 0; c < 4; ++c) {
                const int u = c * 256 + tid;
                const int n_l = u >> 4, g = u & 15;
                const int phys = n_l * 128 + ((g * 8) ^ ((n_l & 7) << 4));
                bf16x8 val = *(const bf16x8*)&sarena[phys];
                *(bf16x8*)&outp[(size_t)(nt * 128 + pass * 64 + n_l) * 4096
                                + mt * 128 + g * 8] = val;
            }
            __syncthreads();
        }
    }
}

// ---------------------------------------------------------------------------
// Output projection, 128x128 tile, fp32 row-major out. Same dbuf K-loop.
// Grid: 1D 192, XCD-chunk-swizzled (chunk = 192/8 = 24).
// ---------------------------------------------------------------------------
__launch_bounds__(256, 3)
__global__ void out128(const unsigned short* __restrict__ X,
                       const unsigned short* __restrict__ W,
                       const float* __restrict__ Bv,
                       float* __restrict__ out) {
    __shared__ __align__(16) unsigned short sarena[16384];
    const int tid = threadIdx.x, lane = tid & 63, w = tid >> 6;
    const int r = lane & 15, quad = lane >> 4;
    const int lin = blockIdx.x;                 // 0..191
    const int wk192 = (lin & 7) * 24 + (lin >> 3);
    const int nt = wk192 % 6, mt = wk192 / 6;

    const int c0 = w * 64 + lane, c1 = c0 + 256;
    const unsigned short* xs0 = X + (mt * 128 + (c0 & 127)) * 768 + (c0 >> 7) * 8;
    const unsigned short* xs1 = X + (mt * 128 + (c1 & 127)) * 768 + (c1 >> 7) * 8;
    const unsigned short* ws0 = W + (nt * 128 + (c0 & 127)) * 768 + (c0 >> 7) * 8;
    const unsigned short* ws1 = W + (nt * 128 + (c1 & 127)) * 768 + (c1 >> 7) * 8;

    gl_lds16(xs0, &sarena[w * 512]);
    gl_lds16(xs1, &sarena[2048 + w * 512]);
    gl_lds16(ws0, &sarena[4096 + w * 512]);
    gl_lds16(ws1, &sarena[4096 + 2048 + w * 512]);
    __syncthreads();

    const int wr = (w & 1) * 64, wc = (w >> 1) * 64;
    f32x4 acc[4][4] = {};
    int cur = 0;
#pragma unroll 2
    for (int kt = 0; kt < 24; ++kt) {
        if (kt < 23) {
            const int nx = (cur ^ 1) * 8192;
            gl_lds16(xs0 + (kt + 1) * 32, &sarena[nx + w * 512]);
            gl_lds16(xs1 + (kt + 1) * 32, &sarena[nx + 2048 + w * 512]);
            gl_lds16(ws0 + (kt + 1) * 32, &sarena[nx + 4096 + w * 512]);
            gl_lds16(ws1 + (kt + 1) * 32, &sarena[nx + 4096 + 2048 + w * 512]);
        }
        const unsigned short* ab = &sarena[cur * 8192];
        const unsigned short* bb = ab + 4096;
        bf16x8 af[4], bfr[4];
#pragma unroll
        for (int i = 0; i < 4; ++i)
            af[i] = *(const bf16x8*)&ab[(quad * 128 + wr + i * 16 + r) * 8];
#pragma unroll
        for (int j = 0; j < 4; ++j)
            bfr[j] = *(const bf16x8*)&bb[(quad * 128 + wc + j * 16 + r) * 8];
#pragma unroll
        for (int i = 0; i < 4; ++i)
#pragma unroll
            for (int j = 0; j < 4; ++j)
                acc[i][j] = __builtin_amdgcn_mfma_f32_16x16x32_bf16(af[i], bfr[j], acc[i][j], 0, 0, 0);
        __syncthreads();
        cur ^= 1;
    }
#pragma unroll
    for (int j = 0; j < 4; ++j) {
        const int n = nt * 128 + wc + j * 16 + r;
        const float bias = Bv[n];
#pragma unroll
        for (int i = 0; i < 4; ++i) {
#pragma unroll
            for (int reg = 0; reg < 4; ++reg) {
                const int m = mt * 128 + wr + i * 16 + quad * 4 + reg;
                out[m * 768 + n] = acc[i][j][reg] + bias;
            }
        }
    }
}

// ---------------------------------------------------------------------------
// rel_h / rel_w: per (head, a) 64x64x64 GEMM against gathered rel_pos rows.
// q is pre-scaled by SC=0.125*log2e, so osc=8 yields rel*log2e for BOTH modes.
// ---------------------------------------------------------------------------
__launch_bounds__(256, 4)
__global__ void relk(const unsigned short* __restrict__ qbuf,
                     const unsigned short* __restrict__ rph,
                     const unsigned short* __restrict__ rpw,
                     unsigned short* __restrict__ rh,
                     unsigned short* __restrict__ rw) {
    __shared__ __align__(16) unsigned short abuf[8 * 64 * 8];
    __shared__ __align__(16) unsigned short bbuf[8 * 64 * 8];
    const int tid = threadIdx.x;
    const int lane = tid & 63, w = tid >> 6;
    const int r = lane & 15, quad = lane >> 4;
    const int a = blockIdx.x, h = blockIdx.y, mode = blockIdx.z;
    const unsigned short* rp = mode ? rpw : rph;
    const float osc = 8.0f;  // log2e / SC

#pragma unroll
    for (int gg = 0; gg < 2; ++gg) {
        const int g = w * 2 + gg;
        const int arow = mode ? (h * 4096 + lane * 64 + a) : (h * 4096 + a * 64 + lane);
        gl_lds16(qbuf + arow * 64 + g * 8, &abuf[g * 512]);
        const int bidx = a - lane + 63;
        gl_lds16(rp + bidx * 64 + g * 8, &bbuf[g * 512]);
    }
    __syncthreads();

    f32x4 acc[4] = {};
#pragma unroll
    for (int s = 0; s < 2; ++s) {
        bf16x8 af = *(const bf16x8*)&abuf[((s * 4 + quad) * 64 + w * 16 + r) * 8];
#pragma unroll
        for (int j = 0; j < 4; ++j) {
            bf16x8 bfr = *(const bf16x8*)&bbuf[((s * 4 + quad) * 64 + j * 16 + r) * 8];
            acc[j] = __builtin_amdgcn_mfma_f32_16x16x32_bf16(af, bfr, acc[j], 0, 0, 0);
        }
    }
    unsigned short* out = mode ? rw : rh;
#pragma unroll
    for (int j = 0; j < 4; ++j) {
#pragma unroll
        for (int reg = 0; reg < 4; ++reg) {
            const int m = w * 16 + quad * 4 + reg, n = j * 16 + r;
            const int t = mode ? (h * 4096 + m * 64 + a) : (h * 4096 + a * 64 + m);
            out[t * 64 + n] = f2b(acc[j][reg] * osc);
        }
    }
}

// ---------------------------------------------------------------------------
// Flash attention, split-2: block = 128-query tile (2 qgroups of 16 / wave),
// split sp covers key tiles sp*32..sp*32+31. Fixed softmax ref (m=0).
// R14-proven per-tile structure:
//   issue global_load_dwordx4 (K,V tile t+1 -> 16 staging VGPRs)
//   rh2 <- srh LDS; acc init = rh2+rwL (bias-in-C)
//   -> QK MFMA -> bare v_exp_f32 + pack -> PV MFMA (+ ones-MFMA row-sum l)
//   barrier (vmcnt drain covers loads issued a phase ago)
//   ds_write K/V regs -> LDS ; barrier.
// ---------------------------------------------------------------------------
__launch_bounds__(256, 3)
__global__ void attn2(const unsigned short* __restrict__ qbuf,
                      const unsigned short* __restrict__ kbuf,
                      const unsigned short* __restrict__ vtbuf,
                      const unsigned short* __restrict__ rhb,
                      const unsigned short* __restrict__ rwb,
                      float* __restrict__ po, float* __restrict__ lp) {
    __shared__ __align__(16) unsigned short skb[4096];   // K [d_oct][key][8]
    __shared__ __align__(16) unsigned short svb[4096];   // V^T [scol_oct][d][8]
    __shared__ __align__(16) unsigned short spb[9216];   // P x2 groups, stride 72
    __shared__ __align__(16) unsigned short srh[4096];   // rel_h*L2E, split's 4 octs
    const int tid = threadIdx.x;
    const int lane = tid & 63, w = tid >> 6;
    const int r = lane & 15, quad = lane >> 4;
    const int qt = blockIdx.x, h = blockIdx.y, sp = blockIdx.z;

    // srh: rel_h*log2e, this split's 4 ki-octs
#pragma unroll
    for (int i = 0; i < 2; ++i) {
        const int ql = (w & 1) * 64 + lane;
        gl_lds16(rhb + (h * 4096 + qt * 128 + ql) * 64 + (sp * 4 + i * 2 + (w >> 1)) * 8,
                 &srh[(i * 256 + w * 64) * 8]);
    }
    // per-thread K/V staging sources (16B per lane per oct; octs w*2, w*2+1)
    const unsigned short* ksrc = kbuf + (size_t)(h * 4096 + lane) * 64 + w * 16;
    const unsigned short* vsrc = vtbuf + (size_t)(h * 64 + lane) * 4096 + w * 16;
    u32x4 kp0, kp1, vp0, vp1;
    {
        const int t0 = sp * 32;
        kp0 = *(const u32x4*)(ksrc + (size_t)t0 * 4096);
        kp1 = *(const u32x4*)(ksrc + (size_t)t0 * 4096 + 8);
        vp0 = *(const u32x4*)(vsrc + t0 * 64);
        vp1 = *(const u32x4*)(vsrc + t0 * 64 + 8);
    }
    bf16x8 qf[2][2];
#pragma unroll
    for (int g = 0; g < 2; ++g) {
        const unsigned short* qrow =
            qbuf + (h * 4096 + qt * 128 + g * 64 + w * 16 + r) * 64;
        qf[g][0] = *(const bf16x8*)(qrow + quad * 8);
        qf[g][1] = *(const bf16x8*)(qrow + 32 + quad * 8);
    }
    float rwL[2][4][4];
#pragma unroll
    for (int g = 0; g < 2; ++g) {
        const unsigned short* rwrow = rwb + (h * 4096 + qt * 128 + g * 64) * 64;
#pragma unroll
        for (int reg = 0; reg < 4; ++reg) {
            const int ql = w * 16 + quad * 4 + reg;
#pragma unroll
            for (int j = 0; j < 4; ++j)
                rwL[g][j][reg] = b2f(rwrow[ql * 64 + j * 16 + r]);  // already *log2e
        }
    }
    bf16x8 onesf;
#pragma unroll
    for (int i = 0; i < 8; ++i) onesf[i] = (short)0x3F80;  // bf16 1.0

    f32x4 lacc[2] = {};
    f32x4 oacc[2][4] = {};
    __syncthreads();                 // srh staged + tile-0 loads complete
    *(u32x4*)&skb[(w * 128 + lane) * 8]      = kp0;
    *(u32x4*)&skb[(w * 128 + 64 + lane) * 8] = kp1;
    *(u32x4*)&svb[(w * 128 + lane) * 8]      = vp0;
    *(u32x4*)&svb[(w * 128 + 64 + lane) * 8] = vp1;
    __syncthreads();                 // tile-0 visible

    for (int tl = 0; tl < 32; ++tl) {
        const int t = sp * 32 + tl;
        if (tl < 31) {               // issue next-tile loads (awaited at barrier1)
            kp0 = *(const u32x4*)(ksrc + (size_t)(t + 1) * 4096);
            kp1 = *(const u32x4*)(ksrc + (size_t)(t + 1) * 4096 + 8);
            vp0 = *(const u32x4*)(vsrc + (t + 1) * 64);
            vp1 = *(const u32x4*)(vsrc + (t + 1) * 64 + 8);
        }
        // bias-in-C: acc starts at rh+rw (both already in log2 units)
        float rh2f[8];
#pragma unroll
        for (int i = 0; i < 8; ++i)
            rh2f[i] = b2f(srh[((tl >> 3) * 128 + (i >> 2) * 64 + w * 16
                               + quad * 4 + (i & 3)) * 8 + (t & 7)]);
        f32x4 s0[4], s1[4];
#pragma unroll
        for (int j = 0; j < 4; ++j)
#pragma unroll
            for (int reg = 0; reg < 4; ++reg) {
                s0[j][reg] = rh2f[reg]     + rwL[0][j][reg];
                s1[j][reg] = rh2f[4 + reg] + rwL[1][j][reg];
            }
        // S for both qgroups; kf read once, used twice
        __builtin_amdgcn_s_setprio(1);
#pragma unroll
        for (int s2 = 0; s2 < 2; ++s2) {
#pragma unroll
            for (int j = 0; j < 4; ++j) {
                bf16x8 kf = *(const bf16x8*)&skb[((s2 * 4 + quad) * 64 + j * 16 + r) * 8];
                s0[j] = __builtin_amdgcn_mfma_f32_16x16x32_bf16(qf[0][s2], kf, s0[j], 0, 0, 0);
                s1[j] = __builtin_amdgcn_mfma_f32_16x16x32_bf16(qf[1][s2], kf, s1[j], 0, 0, 0);
            }
        }
        __builtin_amdgcn_s_setprio(0);
        // softmax: bare v_exp_f32 (arg already = score*SC + bias, log2 units)
#pragma unroll
        for (int g = 0; g < 2; ++g) {
#pragma unroll
            for (int reg = 0; reg < 4; ++reg) {
                unsigned int u[4];
#pragma unroll
                for (int j = 0; j < 4; ++j) {
                    const float p = __builtin_amdgcn_exp2f(g ? s1[j][reg] : s0[j][reg]);
                    union { float f; unsigned int q; } cv; cv.f = p;
                    u[j] = cv.q;
                }
                u32x2 d;
                d.x = __builtin_amdgcn_perm(u[1], u[0], 0x07060302);
                d.y = __builtin_amdgcn_perm(u[3], u[2], 0x07060302);
                *(u32x2*)&spb[g * 4608 + w * 1152 + (quad * 4 + reg) * 72 + r * 4] = d;
            }
        }
        // PV: vf read once, used twice; l row-sum via ones-MFMA
        __builtin_amdgcn_s_setprio(1);
#pragma unroll
        for (int s = 0; s < 2; ++s) {
            bf16x8 pf0 = *(const bf16x8*)&spb[w * 1152 + r * 72 + s * 32 + quad * 8];
            bf16x8 pf1 = *(const bf16x8*)&spb[4608 + w * 1152 + r * 72 + s * 32 + quad * 8];
            lacc[0] = __builtin_amdgcn_mfma_f32_16x16x32_bf16(pf0, onesf, lacc[0], 0, 0, 0);
            lacc[1] = __builtin_amdgcn_mfma_f32_16x16x32_bf16(pf1, onesf, lacc[1], 0, 0, 0);
#pragma unroll
            for (int j = 0; j < 4; ++j) {
                bf16x8 vf = *(const bf16x8*)&svb[((s * 4 + quad) * 64 + j * 16 + r) * 8];
                oacc[0][j] = __builtin_amdgcn_mfma_f32_16x16x32_bf16(pf0, vf, oacc[0][j], 0, 0, 0);
                oacc[1][j] = __builtin_amdgcn_mfma_f32_16x16x32_bf16(pf1, vf, oacc[1][j], 0, 0, 0);
            }
        }
        __builtin_amdgcn_s_setprio(0);

        __syncthreads();             // skb/svb reads retired; vmcnt drain
                                     // covers loads issued a compute-phase ago
        if (tl < 31) {
            *(u32x4*)&skb[(w * 128 + lane) * 8]      = kp0;
            *(u32x4*)&skb[(w * 128 + 64 + lane) * 8] = kp1;
            *(u32x4*)&svb[(w * 128 + lane) * 8]      = vp0;
            *(u32x4*)&svb[(w * 128 + 64 + lane) * 8] = vp1;
        }
        __syncthreads();             // next tile visible (lgkm drain only)
    }
    // epilogue: store partials (lacc already holds full per-query row sums)
    const size_t pbase = ((size_t)(sp * 12 + h) * 4096 + qt * 128);
#pragma unroll
    for (int g = 0; g < 2; ++g) {
        const int qrow = g * 64 + w * 16 + quad * 4;
#pragma unroll
        for (int reg = 0; reg < 4; ++reg) {
#pragma unroll
            for (int j = 0; j < 4; ++j)
                po[(pbase + qrow + reg) * 64 + j * 16 + r] = oacc[g][j][reg];
            if (r == 0) lp[pbase + qrow + reg] = lacc[g][reg];
        }
    }
}

// ---------------------------------------------------------------------------
// Combine split-2 partials: ab[t][h*64+d] = (po0+po1)/(l0+l1) as bf16.
// ---------------------------------------------------------------------------
__global__ __launch_bounds__(256) void combine(const float* __restrict__ po,
                                               const float* __restrict__ lp,
                                               unsigned short* __restrict__ ab) {
    const unsigned int idx = blockIdx.x * 256 + threadIdx.x;  // 0..393215
    const unsigned int tok = idx / 96u;
    const unsigned int part = idx - tok * 96u;
    const int c = part * 8, h = c >> 6, d = c & 63;
    const float* p0 = po + ((size_t)h * 4096 + tok) * 64 + d;
    const float* p1 = po + ((size_t)(12 + h) * 4096 + tok) * 64 + d;
    const float inv = 1.f / (lp[h * 4096 + tok] + lp[(12 + h) * 4096 + tok]);
    const float4 a0 = *(const float4*)p0, b0 = *(const float4*)(p0 + 4);
    const float4 a1 = *(const float4*)p1, b1 = *(const float4*)(p1 + 4);
    s16x4 o0, o1;
    o0[0] = (short)f2b((a0.x + a1.x) * inv); o0[1] = (short)f2b((a0.y + a1.y) * inv);
    o0[2] = (short)f2b((a0.z + a1.z) * inv); o0[3] = (short)f2b((a0.w + a1.w) * inv);
    o1[0] = (short)f2b((b0.x + b1.x) * inv); o1[1] = (short)f2b((b0.y + b1.y) * inv);
    o1[2] = (short)f2b((b0.z + b1.z) * inv); o1[3] = (short)f2b((b0.w + b1.w) * inv);
    unsigned short* dst = ab + (size_t)tok * 768 + c;
    *(s16x4*)dst = o0;
    *(s16x4*)(dst + 4) = o1;
}

// ---------------------------------------------------------------------------
extern "C" void kernel_launch(void* const* d_in, const int* in_sizes, int n_in,
                              void* d_out, int out_size, void* d_ws, size_t ws_size,
                              hipStream_t stream) {
    const float* hs  = (const float*)d_in[0];
    const float* wq  = (const float*)d_in[1];
    const float* bq  = (const float*)d_in[2];
    const float* wk  = (const float*)d_in[3];
    const float* bk  = (const float*)d_in[4];
    const float* wv  = (const float*)d_in[5];
    const float* bv  = (const float*)d_in[6];
    const float* wo  = (const float*)d_in[7];
    const float* bo  = (const float*)d_in[8];
    const float* rph = (const float*)d_in[9];
    const float* rpw = (const float*)d_in[10];

    unsigned short* ws = (unsigned short*)d_ws;
    const int HS = 3145728, WN = 589824, RP = 8128;
    const int HB = 12 * 4096 * 64;
    unsigned short* hsb  = ws;
    unsigned short* wqb  = hsb  + HS;
    unsigned short* wkb  = wqb  + WN;
    unsigned short* wvb  = wkb  + WN;
    unsigned short* wob  = wvb  + WN;
    unsigned short* rphb = wob  + WN;
    unsigned short* rpwb = rphb + RP;
    unsigned short* qb   = rpwb + RP;          // q*SC [h][t][d]
    unsigned short* kb   = qb   + HB;          // k    [h][t][d]
    unsigned short* vtb  = kb   + HB;          // v^T  [h][d][t], token-permuted
    unsigned short* rhb  = vtb  + HB;          // rel_h*log2e [h][t][ki]
    unsigned short* rwb  = rhb  + HB;          // rel_w*log2e [h][t][kj]
    unsigned short* ab   = rwb  + HB;          // attn out [t][768]
    float* po = (float*)(ab + HB);             // O_num partials [2][12][4096][64]
    float* lp = po + 2 * 12 * 4096 * 64;       // l partials [2][12][4096]

    cvt_bf16<<<dim3((1380320 + 255) / 256), 256, 0, stream>>>(
        hs, wq, wk, wv, wo, rph, rpw, hsb);
    qkv128<<<dim3(576), 256, 0, stream>>>(
        hsb, wqb, wkb, wvb, bq, bk, bv, qb, kb, vtb);
    relk<<<dim3(64, 12, 2), 256, 0, stream>>>(qb, rphb, rpwb, rhb, rwb);
    attn2<<<dim3(32, 12, 2), 256, 0, stream>>>(qb, kb, vtb, rhb, rwb, po, lp);
    combine<<<dim3(1536), 256, 0, stream>>>(po, lp, ab);
    out128<<<dim3(192), 256, 0, stream>>>(ab, wob, bo, (float*)d_out);
}

// Round 9
// 225.346 us; speedup vs baseline: 1.7052x; 1.0025x over previous
//
#include <hip/hip_runtime.h>

// ---------------------------------------------------------------------------
// SAM vision attention (B=1, H=W=64, C=768, 12 heads x hd=64). fp32 I/O.
// cvt -> QKV proj (128-tile) -> rel_h/rel_w -> flash attn (split-2, 32 q/wave)
//   -> combine -> out proj
// MFMA v_mfma_f32_16x16x32_bf16 layouts (guide-verified m89/m91):
//   A/B frag: [m|n = lane&15][k = (lane>>4)*8 + j]   (8 bf16 / lane, b128)
//   C/D     : col = lane&15, row = (lane>>4)*4 + reg (4 f32 / lane)
// R18 = R17 (225.9us banked) + XCD chunk swizzle on attn2's grid.
// Post-mortem ledger:
//   R10 (78.5us): reg-staged K/V, srh LDS, 2 barriers/tile. Proven base.
//   R11 (90.9us): gl_lds dbuf single-barrier REGRESSED (m99/m100 repro).
//   R12 (90.3us): per-tile scalar rel_h globals stall barrier drains.
//   R13 (285us!): K/V in regs -> VGPR demand >> alloc -> scratch spill.
//   R14 (75.8us): R10 staging + math (Q pre-scale, bias-in-C, bare exp2). ✓
//   R15 (228us!): __launch_bounds__(256,4) stepped VGPR cap to 64 -> spill.
//   R16 (78.2us): split-4: occupancy stayed 26.8%, costs doubled. Dead end.
//   R17 (225.9 total): R14 attn2 + qkv/out XCD swizzle (+3us). ✓
//   R18: attn2 grid (32,12,2) has qt fastest -> 32 blocks sharing a 512KB
//        K/V panel round-robin over 8 XCDs; each XCD cycles all 24 panels
//        (>> 4MB L2) -> prefetches miss to L3/HBM, exposed at the barrier
//        vmcnt drain (FETCH 58.4MB vs ~29 ideal). Chunked map gives each XCD
//        3 contiguous panels: prefetch hits own L2 (~200cy < compute phase).
//   Closed levers: attn2 skb/svb dbuf (1-barrier) needs 59392B LDS -> 2
//   blk/CU, occupancy loss; bank conflicts 0.8% (negligible); occupancy
//   increase (R15/R16) no help.
// Math (validated R11/R12/R14): Q pre-scaled by SC=0.125*log2e in qkv;
// relk osc=8 so rhb/rwb hold rel*log2e; attn2 inits QK accumulator to rh+rw
// (bias-in-C); softmax is a bare v_exp_f32.
// ---------------------------------------------------------------------------

typedef __attribute__((ext_vector_type(8))) short bf16x8;
typedef __attribute__((ext_vector_type(4))) float f32x4;
typedef __attribute__((ext_vector_type(4))) short s16x4;
typedef __attribute__((ext_vector_type(2))) unsigned int u32x2;
typedef __attribute__((ext_vector_type(4))) unsigned int u32x4;

__device__ __forceinline__ float b2f(unsigned short h) {
    union { unsigned int u; float f; } v; v.u = ((unsigned int)h) << 16; return v.f;
}
__device__ __forceinline__ unsigned short f2b(float f) {
    union { float f; unsigned int u; } v; v.f = f;
    unsigned int r = v.u + 0x7FFFu + ((v.u >> 16) & 1u);  // RNE
    return (unsigned short)(r >> 16);
}
__device__ __forceinline__ void gl_lds16(const void* g, void* l) {
    __builtin_amdgcn_global_load_lds(
        (const __attribute__((address_space(1))) void*)g,
        (__attribute__((address_space(3))) void*)l, 16, 0, 0);
}

// ---------------------------------------------------------------------------
// fp32 -> bf16 bulk convert into one contiguous region (quad-indexed).
// ---------------------------------------------------------------------------
__global__ __launch_bounds__(256) void cvt_bf16(
        const float* __restrict__ hs, const float* __restrict__ wq,
        const float* __restrict__ wk, const float* __restrict__ wv,
        const float* __restrict__ wo, const float* __restrict__ rph,
        const float* __restrict__ rpw, unsigned short* __restrict__ dst) {
    const int idx = blockIdx.x * 256 + threadIdx.x;
    if (idx >= 1380320) return;
    const float* src;
    int off;
    if      (idx < 786432)  { src = hs;  off = idx; }
    else if (idx < 933888)  { src = wq;  off = idx - 786432; }
    else if (idx < 1081344) { src = wk;  off = idx - 933888; }
    else if (idx < 1228800) { src = wv;  off = idx - 1081344; }
    else if (idx < 1376256) { src = wo;  off = idx - 1228800; }
    else if (idx < 1378288) { src = rph; off = idx - 1376256; }
    else                    { src = rpw; off = idx - 1378288; }
    const float4 v = ((const float4*)src)[off];
    s16x4 o;
    o[0] = (short)f2b(v.x); o[1] = (short)f2b(v.y);
    o[2] = (short)f2b(v.z); o[3] = (short)f2b(v.w);
    *(s16x4*)(dst + (size_t)idx * 4) = o;
}

// ---------------------------------------------------------------------------
// Fused QKV projection, 128x128 tile. z: 0->q (PRE-SCALED by 0.125*log2e),
// 1->k [n>>6][m][n&63]; 2->v^T token-PERMUTED, stored via LDS transpose.
// K-loop: double-buffered gl_lds, one barrier per step.
// Grid: 1D 576, XCD-chunk-swizzled (chunk = 576/8 = 72).
// ---------------------------------------------------------------------------
__launch_bounds__(256, 3)
__global__ void qkv128(const unsigned short* __restrict__ X,
                       const unsigned short* __restrict__ Wq,
                       const unsigned short* __restrict__ Wk,
                       const unsigned short* __restrict__ Wv,
                       const float* __restrict__ bq,
                       const float* __restrict__ bk,
                       const float* __restrict__ bv,
                       unsigned short* __restrict__ qb,
                       unsigned short* __restrict__ kb,
                       unsigned short* __restrict__ vtb) {
    __shared__ __align__(16) unsigned short sarena[16384];  // 2 x (A 4096 + B 4096)
    const int tid = threadIdx.x, lane = tid & 63, w = tid >> 6;
    const int r = lane & 15, quad = lane >> 4;
    // XCD chunked swizzle: lin%8 = XCD -> give it works [x*72, x*72+72)
    const int lin = blockIdx.x;                 // 0..575
    const int wk576 = (lin & 7) * 72 + (lin >> 3);
    const int nt = wk576 % 6, mt = (wk576 / 6) & 31, z = wk576 / 192;
    const unsigned short* W  = (z == 0) ? Wq : (z == 1) ? Wk : Wv;
    const float*          Bv = (z == 0) ? bq : (z == 1) ? bk : bv;
    unsigned short*     outp = (z == 0) ? qb : (z == 1) ? kb : vtb;
    const float qsc = (z == 0) ? 0.18033688f : 1.0f;  // 0.125*log2(e)

    const int c0 = w * 64 + lane, c1 = c0 + 256;
    const unsigned short* xs0 = X + (mt * 128 + (c0 & 127)) * 768 + (c0 >> 7) * 8;
    const unsigned short* xs1 = X + (mt * 128 + (c1 & 127)) * 768 + (c1 >> 7) * 8;
    const unsigned short* ws0 = W + (nt * 128 + (c0 & 127)) * 768 + (c0 >> 7) * 8;
    const unsigned short* ws1 = W + (nt * 128 + (c1 & 127)) * 768 + (c1 >> 7) * 8;

    // prologue: stage kt=0 into buffer 0
    gl_lds16(xs0, &sarena[w * 512]);
    gl_lds16(xs1, &sarena[2048 + w * 512]);
    gl_lds16(ws0, &sarena[4096 + w * 512]);
    gl_lds16(ws1, &sarena[4096 + 2048 + w * 512]);
    __syncthreads();

    const int wr = (w & 1) * 64, wc = (w >> 1) * 64;
    f32x4 acc[4][4] = {};
    int cur = 0;
#pragma unroll 2
    for (int kt = 0; kt < 24; ++kt) {
        if (kt < 23) {              // issue next K-step into alt buffer
            const int nx = (cur ^ 1) * 8192;
            gl_lds16(xs0 + (kt + 1) * 32, &sarena[nx + w * 512]);
            gl_lds16(xs1 + (kt + 1) * 32, &sarena[nx + 2048 + w * 512]);
            gl_lds16(ws0 + (kt + 1) * 32, &sarena[nx + 4096 + w * 512]);
            gl_lds16(ws1 + (kt + 1) * 32, &sarena[nx + 4096 + 2048 + w * 512]);
        }
        const unsigned short* ab = &sarena[cur * 8192];
        const unsigned short* bb = ab + 4096;
        bf16x8 af[4], bfr[4];
#pragma unroll
        for (int i = 0; i < 4; ++i)
            af[i] = *(const bf16x8*)&ab[(quad * 128 + wr + i * 16 + r) * 8];
#pragma unroll
        for (int j = 0; j < 4; ++j)
            bfr[j] = *(const bf16x8*)&bb[(quad * 128 + wc + j * 16 + r) * 8];
#pragma unroll
        for (int i = 0; i < 4; ++i)
#pragma unroll
            for (int j = 0; j < 4; ++j)
                acc[i][j] = __builtin_amdgcn_mfma_f32_16x16x32_bf16(af[i], bfr[j], acc[i][j], 0, 0, 0);
        __syncthreads();            // drains vmcnt(0): next tile landed+visible
        cur ^= 1;
    }
    if (z < 2) {
#pragma unroll
        for (int j = 0; j < 4; ++j) {
            const int n = nt * 128 + wc + j * 16 + r;
            const float bias = Bv[n];
            const int nhi = n >> 6, nlo = n & 63;
#pragma unroll
            for (int i = 0; i < 4; ++i) {
#pragma unroll
                for (int reg = 0; reg < 4; ++reg) {
                    const int m = mt * 128 + wr + i * 16 + quad * 4 + reg;
                    outp[(nhi * 4096 + m) * 64 + nlo] = f2b((acc[i][j][reg] + bias) * qsc);
                }
            }
        }
    } else {
#pragma unroll
        for (int pass = 0; pass < 2; ++pass) {
            if ((w >> 1) == pass) {
#pragma unroll
                for (int j = 0; j < 4; ++j) {
                    const int n_l = j * 16 + r;
                    const float bias = Bv[nt * 128 + pass * 64 + n_l];
                    const int sw = (n_l & 7) << 4;
#pragma unroll
                    for (int reg = 0; reg < 4; ++reg) {
                        const int tokb = (wr + (quad * 4 + reg) * 4) ^ sw;
                        u32x2 d2;
                        d2.x = (unsigned int)f2b(acc[0][j][reg] + bias)
                             | ((unsigned int)f2b(acc[1][j][reg] + bias) << 16);
                        d2.y = (unsigned int)f2b(acc[2][j][reg] + bias)
                             | ((unsigned int)f2b(acc[3][j][reg] + bias) << 16);
                        *(u32x2*)&sarena[n_l * 128 + tokb] = d2;
                    }
                }
            }
            __syncthreads();
#pragma unroll
            for (int c = 0; c < 4; ++c) {
                const int u = c * 256 + tid;
                const int n_l = u >> 4, g = u & 15;
                const int phys = n_l * 128 + ((g * 8) ^ ((n_l & 7) << 4));
                bf16x8 val = *(const bf16x8*)&sarena[phys];
                *(bf16x8*)&outp[(size_t)(nt * 128 + pass * 64 + n_l) * 4096
                                + mt * 128 + g * 8] = val;
            }
            __syncthreads();
        }
    }
}

// ---------------------------------------------------------------------------
// Output projection, 128x128 tile, fp32 row-major out. Same dbuf K-loop.
// Grid: 1D 192, XCD-chunk-swizzled (chunk = 192/8 = 24).
// ---------------------------------------------------------------------------
__launch_bounds__(256, 3)
__global__ void out128(const unsigned short* __restrict__ X,
                       const unsigned short* __restrict__ W,
                       const float* __restrict__ Bv,
                       float* __restrict__ out) {
    __shared__ __align__(16) unsigned short sarena[16384];
    const int tid = threadIdx.x, lane = tid & 63, w = tid >> 6;
    const int r = lane & 15, quad = lane >> 4;
    const int lin = blockIdx.x;                 // 0..191
    const int wk192 = (lin & 7) * 24 + (lin >> 3);
    const int nt = wk192 % 6, mt = wk192 / 6;

    const int c0 = w * 64 + lane, c1 = c0 + 256;
    const unsigned short* xs0 = X + (mt * 128 + (c0 & 127)) * 768 + (c0 >> 7) * 8;
    const unsigned short* xs1 = X + (mt * 128 + (c1 & 127)) * 768 + (c1 >> 7) * 8;
    const unsigned short* ws0 = W + (nt * 128 + (c0 & 127)) * 768 + (c0 >> 7) * 8;
    const unsigned short* ws1 = W + (nt * 128 + (c1 & 127)) * 768 + (c1 >> 7) * 8;

    gl_lds16(xs0, &sarena[w * 512]);
    gl_lds16(xs1, &sarena[2048 + w * 512]);
    gl_lds16(ws0, &sarena[4096 + w * 512]);
    gl_lds16(ws1, &sarena[4096 + 2048 + w * 512]);
    __syncthreads();

    const int wr = (w & 1) * 64, wc = (w >> 1) * 64;
    f32x4 acc[4][4] = {};
    int cur = 0;
#pragma unroll 2
    for (int kt = 0; kt < 24; ++kt) {
        if (kt < 23) {
            const int nx = (cur ^ 1) * 8192;
            gl_lds16(xs0 + (kt + 1) * 32, &sarena[nx + w * 512]);
            gl_lds16(xs1 + (kt + 1) * 32, &sarena[nx + 2048 + w * 512]);
            gl_lds16(ws0 + (kt + 1) * 32, &sarena[nx + 4096 + w * 512]);
            gl_lds16(ws1 + (kt + 1) * 32, &sarena[nx + 4096 + 2048 + w * 512]);
        }
        const unsigned short* ab = &sarena[cur * 8192];
        const unsigned short* bb = ab + 4096;
        bf16x8 af[4], bfr[4];
#pragma unroll
        for (int i = 0; i < 4; ++i)
            af[i] = *(const bf16x8*)&ab[(quad * 128 + wr + i * 16 + r) * 8];
#pragma unroll
        for (int j = 0; j < 4; ++j)
            bfr[j] = *(const bf16x8*)&bb[(quad * 128 + wc + j * 16 + r) * 8];
#pragma unroll
        for (int i = 0; i < 4; ++i)
#pragma unroll
            for (int j = 0; j < 4; ++j)
                acc[i][j] = __builtin_amdgcn_mfma_f32_16x16x32_bf16(af[i], bfr[j], acc[i][j], 0, 0, 0);
        __syncthreads();
        cur ^= 1;
    }
#pragma unroll
    for (int j = 0; j < 4; ++j) {
        const int n = nt * 128 + wc + j * 16 + r;
        const float bias = Bv[n];
#pragma unroll
        for (int i = 0; i < 4; ++i) {
#pragma unroll
            for (int reg = 0; reg < 4; ++reg) {
                const int m = mt * 128 + wr + i * 16 + quad * 4 + reg;
                out[m * 768 + n] = acc[i][j][reg] + bias;
            }
        }
    }
}

// ---------------------------------------------------------------------------
// rel_h / rel_w: per (head, a) 64x64x64 GEMM against gathered rel_pos rows.
// q is pre-scaled by SC=0.125*log2e, so osc=8 yields rel*log2e for BOTH modes.
// ---------------------------------------------------------------------------
__launch_bounds__(256, 4)
__global__ void relk(const unsigned short* __restrict__ qbuf,
                     const unsigned short* __restrict__ rph,
                     const unsigned short* __restrict__ rpw,
                     unsigned short* __restrict__ rh,
                     unsigned short* __restrict__ rw) {
    __shared__ __align__(16) unsigned short abuf[8 * 64 * 8];
    __shared__ __align__(16) unsigned short bbuf[8 * 64 * 8];
    const int tid = threadIdx.x;
    const int lane = tid & 63, w = tid >> 6;
    const int r = lane & 15, quad = lane >> 4;
    const int a = blockIdx.x, h = blockIdx.y, mode = blockIdx.z;
    const unsigned short* rp = mode ? rpw : rph;
    const float osc = 8.0f;  // log2e / SC

#pragma unroll
    for (int gg = 0; gg < 2; ++gg) {
        const int g = w * 2 + gg;
        const int arow = mode ? (h * 4096 + lane * 64 + a) : (h * 4096 + a * 64 + lane);
        gl_lds16(qbuf + arow * 64 + g * 8, &abuf[g * 512]);
        const int bidx = a - lane + 63;
        gl_lds16(rp + bidx * 64 + g * 8, &bbuf[g * 512]);
    }
    __syncthreads();

    f32x4 acc[4] = {};
#pragma unroll
    for (int s = 0; s < 2; ++s) {
        bf16x8 af = *(const bf16x8*)&abuf[((s * 4 + quad) * 64 + w * 16 + r) * 8];
#pragma unroll
        for (int j = 0; j < 4; ++j) {
            bf16x8 bfr = *(const bf16x8*)&bbuf[((s * 4 + quad) * 64 + j * 16 + r) * 8];
            acc[j] = __builtin_amdgcn_mfma_f32_16x16x32_bf16(af, bfr, acc[j], 0, 0, 0);
        }
    }
    unsigned short* out = mode ? rw : rh;
#pragma unroll
    for (int j = 0; j < 4; ++j) {
#pragma unroll
        for (int reg = 0; reg < 4; ++reg) {
            const int m = w * 16 + quad * 4 + reg, n = j * 16 + r;
            const int t = mode ? (h * 4096 + m * 64 + a) : (h * 4096 + a * 64 + m);
            out[t * 64 + n] = f2b(acc[j][reg] * osc);
        }
    }
}

// ---------------------------------------------------------------------------
// Flash attention, split-2: block = 128-query tile (2 qgroups of 16 / wave),
// split sp covers key tiles sp*32..sp*32+31. Fixed softmax ref (m=0).
// R14-proven per-tile structure:
//   issue global_load_dwordx4 (K,V tile t+1 -> 16 staging VGPRs)
//   rh2 <- srh LDS; acc init = rh2+rwL (bias-in-C)
//   -> QK MFMA -> bare v_exp_f32 + pack -> PV MFMA (+ ones-MFMA row-sum l)
//   barrier (vmcnt drain covers loads issued a phase ago)
//   ds_write K/V regs -> LDS ; barrier.
// R18: grid flattened to 768, XCD-chunked (chunk = 96 = 3 (h,sp) panels):
// each XCD's L2 sees one 512KB K/V panel at a time, reused by 32 qt-blocks
// -> prefetch hits own-XCD L2 (~200cy), lands within the compute phase.
// ---------------------------------------------------------------------------
__launch_bounds__(256, 3)
__global__ void attn2(const unsigned short* __restrict__ qbuf,
                      const unsigned short* __restrict__ kbuf,
                      const unsigned short* __restrict__ vtbuf,
                      const unsigned short* __restrict__ rhb,
                      const unsigned short* __restrict__ rwb,
                      float* __restrict__ po, float* __restrict__ lp) {
    __shared__ __align__(16) unsigned short skb[4096];   // K [d_oct][key][8]
    __shared__ __align__(16) unsigned short svb[4096];   // V^T [scol_oct][d][8]
    __shared__ __align__(16) unsigned short spb[9216];   // P x2 groups, stride 72
    __shared__ __align__(16) unsigned short srh[4096];   // rel_h*L2E, split's 4 octs
    const int tid = threadIdx.x;
    const int lane = tid & 63, w = tid >> 6;
    const int r = lane & 15, quad = lane >> 4;
    // XCD chunked swizzle: work = (bid%8)*96 + bid/8; decomp h|sp|qt with qt
    // fastest -> each XCD gets 3 whole (h,sp) K/V panels, contiguous in time.
    const int bid = blockIdx.x;                  // 0..767
    const int wk768 = (bid & 7) * 96 + (bid >> 3);
    const int h = wk768 >> 6, sp = (wk768 >> 5) & 1, qt = wk768 & 31;

    // srh: rel_h*log2e, this split's 4 ki-octs
#pragma unroll
    for (int i = 0; i < 2; ++i) {
        const int ql = (w & 1) * 64 + lane;
        gl_lds16(rhb + (h * 4096 + qt * 128 + ql) * 64 + (sp * 4 + i * 2 + (w >> 1)) * 8,
                 &srh[(i * 256 + w * 64) * 8]);
    }
    // per-thread K/V staging sources (16B per lane per oct; octs w*2, w*2+1)
    const unsigned short* ksrc = kbuf + (size_t)(h * 4096 + lane) * 64 + w * 16;
    const unsigned short* vsrc = vtbuf + (size_t)(h * 64 + lane) * 4096 + w * 16;
    u32x4 kp0, kp1, vp0, vp1;
    {
        const int t0 = sp * 32;
        kp0 = *(const u32x4*)(ksrc + (size_t)t0 * 4096);
        kp1 = *(const u32x4*)(ksrc + (size_t)t0 * 4096 + 8);
        vp0 = *(const u32x4*)(vsrc + t0 * 64);
        vp1 = *(const u32x4*)(vsrc + t0 * 64 + 8);
    }
    bf16x8 qf[2][2];
#pragma unroll
    for (int g = 0; g < 2; ++g) {
        const unsigned short* qrow =
            qbuf + (h * 4096 + qt * 128 + g * 64 + w * 16 + r) * 64;
        qf[g][0] = *(const bf16x8*)(qrow + quad * 8);
        qf[g][1] = *(const bf16x8*)(qrow + 32 + quad * 8);
    }
    float rwL[2][4][4];
#pragma unroll
    for (int g = 0; g < 2; ++g) {
        const unsigned short* rwrow = rwb + (h * 4096 + qt * 128 + g * 64) * 64;
#pragma unroll
        for (int reg = 0; reg < 4; ++reg) {
            const int ql = w * 16 + quad * 4 + reg;
#pragma unroll
            for (int j = 0; j < 4; ++j)
                rwL[g][j][reg] = b2f(rwrow[ql * 64 + j * 16 + r]);  // already *log2e
        }
    }
    bf16x8 onesf;
#pragma unroll
    for (int i = 0; i < 8; ++i) onesf[i] = (short)0x3F80;  // bf16 1.0

    f32x4 lacc[2] = {};
    f32x4 oacc[2][4] = {};
    __syncthreads();                 // srh staged + tile-0 loads complete
    *(u32x4*)&skb[(w * 128 + lane) * 8]      = kp0;
    *(u32x4*)&skb[(w * 128 + 64 + lane) * 8] = kp1;
    *(u32x4*)&svb[(w * 128 + lane) * 8]      = vp0;
    *(u32x4*)&svb[(w * 128 + 64 + lane) * 8] = vp1;
    __syncthreads();                 // tile-0 visible

    for (int tl = 0; tl < 32; ++tl) {
        const int t = sp * 32 + tl;
        if (tl < 31) {               // issue next-tile loads (awaited at barrier1)
            kp0 = *(const u32x4*)(ksrc + (size_t)(t + 1) * 4096);
            kp1 = *(const u32x4*)(ksrc + (size_t)(t + 1) * 4096 + 8);
            vp0 = *(const u32x4*)(vsrc + (t + 1) * 64);
            vp1 = *(const u32x4*)(vsrc + (t + 1) * 64 + 8);
        }
        // bias-in-C: acc starts at rh+rw (both already in log2 units)
        float rh2f[8];
#pragma unroll
        for (int i = 0; i < 8; ++i)
            rh2f[i] = b2f(srh[((tl >> 3) * 128 + (i >> 2) * 64 + w * 16
                               + quad * 4 + (i & 3)) * 8 + (t & 7)]);
        f32x4 s0[4], s1[4];
#pragma unroll
        for (int j = 0; j < 4; ++j)
#pragma unroll
            for (int reg = 0; reg < 4; ++reg) {
                s0[j][reg] = rh2f[reg]     + rwL[0][j][reg];
                s1[j][reg] = rh2f[4 + reg] + rwL[1][j][reg];
            }
        // S for both qgroups; kf read once, used twice
        __builtin_amdgcn_s_setprio(1);
#pragma unroll
        for (int s2 = 0; s2 < 2; ++s2) {
#pragma unroll
            for (int j = 0; j < 4; ++j) {
                bf16x8 kf = *(const bf16x8*)&skb[((s2 * 4 + quad) * 64 + j * 16 + r) * 8];
                s0[j] = __builtin_amdgcn_mfma_f32_16x16x32_bf16(qf[0][s2], kf, s0[j], 0, 0, 0);
                s1[j] = __builtin_amdgcn_mfma_f32_16x16x32_bf16(qf[1][s2], kf, s1[j], 0, 0, 0);
            }
        }
        __builtin_amdgcn_s_setprio(0);
        // softmax: bare v_exp_f32 (arg already = score*SC + bias, log2 units)
#pragma unroll
        for (int g = 0; g < 2; ++g) {
#pragma unroll
            for (int reg = 0; reg < 4; ++reg) {
                unsigned int u[4];
#pragma unroll
                for (int j = 0; j < 4; ++j) {
                    const float p = __builtin_amdgcn_exp2f(g ? s1[j][reg] : s0[j][reg]);
                    union { float f; unsigned int q; } cv; cv.f = p;
                    u[j] = cv.q;
                }
                u32x2 d;
                d.x = __builtin_amdgcn_perm(u[1], u[0], 0x07060302);
                d.y = __builtin_amdgcn_perm(u[3], u[2], 0x07060302);
                *(u32x2*)&spb[g * 4608 + w * 1152 + (quad * 4 + reg) * 72 + r * 4] = d;
            }
        }
        // PV: vf read once, used twice; l row-sum via ones-MFMA
        __builtin_amdgcn_s_setprio(1);
#pragma unroll
        for (int s = 0; s < 2; ++s) {
            bf16x8 pf0 = *(const bf16x8*)&spb[w * 1152 + r * 72 + s * 32 + quad * 8];
            bf16x8 pf1 = *(const bf16x8*)&spb[4608 + w * 1152 + r * 72 + s * 32 + quad * 8];
            lacc[0] = __builtin_amdgcn_mfma_f32_16x16x32_bf16(pf0, onesf, lacc[0], 0, 0, 0);
            lacc[1] = __builtin_amdgcn_mfma_f32_16x16x32_bf16(pf1, onesf, lacc[1], 0, 0, 0);
#pragma unroll
            for (int j = 0; j < 4; ++j) {
                bf16x8 vf = *(const bf16x8*)&svb[((s * 4 + quad) * 64 + j * 16 + r) * 8];
                oacc[0][j] = __builtin_amdgcn_mfma_f32_16x16x32_bf16(pf0, vf, oacc[0][j], 0, 0, 0);
                oacc[1][j] = __builtin_amdgcn_mfma_f32_16x16x32_bf16(pf1, vf, oacc[1][j], 0, 0, 0);
            }
        }
        __builtin_amdgcn_s_setprio(0);

        __syncthreads();             // skb/svb reads retired; vmcnt drain
                                     // covers loads issued a compute-phase ago
        if (tl < 31) {
            *(u32x4*)&skb[(w * 128 + lane) * 8]      = kp0;
            *(u32x4*)&skb[(w * 128 + 64 + lane) * 8] = kp1;
            *(u32x4*)&svb[(w * 128 + lane) * 8]      = vp0;
            *(u32x4*)&svb[(w * 128 + 64 + lane) * 8] = vp1;
        }
        __syncthreads();             // next tile visible (lgkm drain only)
    }
    // epilogue: store partials (lacc already holds full per-query row sums)
    const size_t pbase = ((size_t)(sp * 12 + h) * 4096 + qt * 128);
#pragma unroll
    for (int g = 0; g < 2; ++g) {
        const int qrow = g * 64 + w * 16 + quad * 4;
#pragma unroll
        for (int reg = 0; reg < 4; ++reg) {
#pragma unroll
            for (int j = 0; j < 4; ++j)
                po[(pbase + qrow + reg) * 64 + j * 16 + r] = oacc[g][j][reg];
            if (r == 0) lp[pbase + qrow + reg] = lacc[g][reg];
        }
    }
}

// ---------------------------------------------------------------------------
// Combine split-2 partials: ab[t][h*64+d] = (po0+po1)/(l0+l1) as bf16.
// ---------------------------------------------------------------------------
__global__ __launch_bounds__(256) void combine(const float* __restrict__ po,
                                               const float* __restrict__ lp,
                                               unsigned short* __restrict__ ab) {
    const unsigned int idx = blockIdx.x * 256 + threadIdx.x;  // 0..393215
    const unsigned int tok = idx / 96u;
    const unsigned int part = idx - tok * 96u;
    const int c = part * 8, h = c >> 6, d = c & 63;
    const float* p0 = po + ((size_t)h * 4096 + tok) * 64 + d;
    const float* p1 = po + ((size_t)(12 + h) * 4096 + tok) * 64 + d;
    const float inv = 1.f / (lp[h * 4096 + tok] + lp[(12 + h) * 4096 + tok]);
    const float4 a0 = *(const float4*)p0, b0 = *(const float4*)(p0 + 4);
    const float4 a1 = *(const float4*)p1, b1 = *(const float4*)(p1 + 4);
    s16x4 o0, o1;
    o0[0] = (short)f2b((a0.x + a1.x) * inv); o0[1] = (short)f2b((a0.y + a1.y) * inv);
    o0[2] = (short)f2b((a0.z + a1.z) * inv); o0[3] = (short)f2b((a0.w + a1.w) * inv);
    o1[0] = (short)f2b((b0.x + b1.x) * inv); o1[1] = (short)f2b((b0.y + b1.y) * inv);
    o1[2] = (short)f2b((b0.z + b1.z) * inv); o1[3] = (short)f2b((b0.w + b1.w) * inv);
    unsigned short* dst = ab + (size_t)tok * 768 + c;
    *(s16x4*)dst = o0;
    *(s16x4*)(dst + 4) = o1;
}

// ---------------------------------------------------------------------------
extern "C" void kernel_launch(void* const* d_in, const int* in_sizes, int n_in,
                              void* d_out, int out_size, void* d_ws, size_t ws_size,
                              hipStream_t stream) {
    const float* hs  = (const float*)d_in[0];
    const float* wq  = (const float*)d_in[1];
    const float* bq  = (const float*)d_in[2];
    const float* wk  = (const float*)d_in[3];
    const float* bk  = (const float*)d_in[4];
    const float* wv  = (const float*)d_in[5];
    const float* bv  = (const float*)d_in[6];
    const float* wo  = (const float*)d_in[7];
    const float* bo  = (const float*)d_in[8];
    const float* rph = (const float*)d_in[9];
    const float* rpw = (const float*)d_in[10];

    unsigned short* ws = (unsigned short*)d_ws;
    const int HS = 3145728, WN = 589824, RP = 8128;
    const int HB = 12 * 4096 * 64;
    unsigned short* hsb  = ws;
    unsigned short* wqb  = hsb  + HS;
    unsigned short* wkb  = wqb  + WN;
    unsigned short* wvb  = wkb  + WN;
    unsigned short* wob  = wvb  + WN;
    unsigned short* rphb = wob  + WN;
    unsigned short* rpwb = rphb + RP;
    unsigned short* qb   = rpwb + RP;          // q*SC [h][t][d]
    unsigned short* kb   = qb   + HB;          // k    [h][t][d]
    unsigned short* vtb  = kb   + HB;          // v^T  [h][d][t], token-permuted
    unsigned short* rhb  = vtb  + HB;          // rel_h*log2e [h][t][ki]
    unsigned short* rwb  = rhb  + HB;          // rel_w*log2e [h][t][kj]
    unsigned short* ab   = rwb  + HB;          // attn out [t][768]
    float* po = (float*)(ab + HB);             // O_num partials [2][12][4096][64]
    float* lp = po + 2 * 12 * 4096 * 64;       // l partials [2][12][4096]

    cvt_bf16<<<dim3((1380320 + 255) / 256), 256, 0, stream>>>(
        hs, wq, wk, wv, wo, rph, rpw, hsb);
    qkv128<<<dim3(576), 256, 0, stream>>>(
        hsb, wqb, wkb, wvb, bq, bk, bv, qb, kb, vtb);
    relk<<<dim3(64, 12, 2), 256, 0, stream>>>(qb, rphb, rpwb, rhb, rwb);
    attn2<<<dim3(768), 256, 0, stream>>>(qb, kb, vtb, rhb, rwb, po, lp);
    combine<<<dim3(1536), 256, 0, stream>>>(po, lp, ab);
    out128<<<dim3(192), 256, 0, stream>>>(ab, wob, bo, (float*)d_out);
}